// Round 9
// baseline (943.599 us; speedup 1.0000x reference)
//
#include <hip/hip_runtime.h>
#include <math.h>

typedef unsigned short u16;
typedef unsigned int u32;
typedef __attribute__((ext_vector_type(8))) short short8;
typedef __attribute__((ext_vector_type(4))) float f32x4;

#define BB 4
#define LSEQ 2048
static const size_t SZ = (size_t)BB * LSEQ * 256; // 2097152

#define NCH 64
#define CT 32

__device__ __forceinline__ float b2f(u32 u) { return __uint_as_float(u); }

// 3-way bf16 split: x = h + m + l - eps, |eps| <= 2^-27 |x|
__device__ __forceinline__ void split3(float x, u16& h, u16& m, u16& l) {
    u32 xu = __float_as_uint(x);
    u32 hu = (xu + 0x7FFFu + ((xu >> 16) & 1u)) & 0xFFFF0000u;
    h = (u16)(hu >> 16);
    float r1 = x - b2f(hu);
    u32 r1u = __float_as_uint(r1);
    u32 mu = (r1u + 0x7FFFu + ((r1u >> 16) & 1u)) & 0xFFFF0000u;
    m = (u16)(mu >> 16);
    float r2 = r1 - b2f(mu);
    u32 lu = __float_as_uint(r2);
    l = (u16)((lu + 0x7FFFu + ((lu >> 16) & 1u)) >> 16);
}

__device__ __forceinline__ float rc3(const u16* __restrict__ h, const u16* __restrict__ m,
                                     const u16* __restrict__ l, size_t i) {
    return b2f((u32)h[i] << 16) + b2f((u32)m[i] << 16) + b2f((u32)l[i] << 16);
}

// ---------------- weight transpose+split: W[mat][K][N] -> planes [mat][n][k] ----------------
__global__ void wsplit_t(const float* __restrict__ W, int Kd, int Nd, int total,
                         u16* __restrict__ oh, u16* __restrict__ om, u16* __restrict__ ol) {
    int idx = blockIdx.x * 256 + threadIdx.x;
    if (idx >= total) return;
    int per = Kd * Nd;
    int mat = idx / per;
    int r = idx - mat * per;
    int n = r / Kd;
    int k = r - n * Kd;
    float v = W[(size_t)mat * per + (size_t)k * Nd + n];
    split3(v, oh[idx], om[idx], ol[idx]);
}

// ---------------- conv weight split: w[co][ci][3] -> planes [tap][co][ci] ----------------
__global__ void wsplit_conv(const float* __restrict__ w, int CI, int total,
                            u16* __restrict__ oh, u16* __restrict__ om, u16* __restrict__ ol) {
    int idx = blockIdx.x * 256 + threadIdx.x;
    if (idx >= total) return;
    int ci = idx % CI;
    int tmp = idx / CI;
    int co = tmp & 255;
    int tap = tmp >> 8;
    float v = w[(co * CI + ci) * 3 + tap];
    split3(v, oh[idx], om[idx], ol[idx]);
}

// ---------------- B/C weight split for bcproj GEMM: [layer][n(64)][k(256)] ----------------
__global__ void wsplit_bc(const float* __restrict__ Bw, const float* __restrict__ Cw,
                          u16* __restrict__ oh, u16* __restrict__ om, u16* __restrict__ ol) {
    int idx = blockIdx.x * 256 + threadIdx.x; // 32768 total
    int layer = idx >> 14;
    int r = idx & 16383;
    int n = r >> 8, k = r & 255;
    int dir = n >> 5, which = (n >> 4) & 1, col = n & 15;
    const float* src = which ? Cw : Bw;
    float v = src[layer * 8192 + dir * 4096 + k * 16 + col];
    split3(v, oh[idx], om[idx], ol[idx]);
}

// ---------------- conv0: Ci=1, Co=128 -> split planes (B,L,128) ----------------
__global__ __launch_bounds__(256) void conv0_k(const float* __restrict__ x, const float* __restrict__ w,
                                               const float* __restrict__ cb, const float* __restrict__ g,
                                               const float* __restrict__ bb, u16* __restrict__ oh,
                                               u16* __restrict__ om, u16* __restrict__ ol) {
    int gid = blockIdx.x * 256 + threadIdx.x;
    int co = gid & 127;
    int l = (gid >> 7) & (LSEQ - 1);
    int b = gid >> 18;
    const float* xr = x + (size_t)b * LSEQ;
    float xm1 = (l > 0) ? xr[l - 1] : 0.f;
    float x0 = xr[l];
    float xp1 = (l < LSEQ - 1) ? xr[l + 1] : 0.f;
    float v = xm1 * w[co * 3] + x0 * w[co * 3 + 1] + xp1 * w[co * 3 + 2] + cb[co];
    v = fmaxf(g[co] * v + bb[co], 0.f);
    size_t o = ((size_t)b * LSEQ + l) * 128 + co;
    split3(v, oh[o], om[o], ol[o]);
}

#define MODE_FP 0
#define MODE_UZ 1
#define MODE_DT 2
#define MODE_OUT 3
#define MODE_BC 4

// ---------------- MFMA GEMM v2: one A-stage (16 rows), loop all N cols in groups of 64 ----------------
// grid: (512, 1, Z). block = 4 waves; wave covers 16 n-cols per group; ng groups.
__global__ __launch_bounds__(256, 2) void mfma_gemm_k(
    const u16* __restrict__ Ah, const u16* __restrict__ Am, const u16* __restrict__ Al,
    const u16* __restrict__ Bh_, const u16* __restrict__ Bm_, const u16* __restrict__ Bl_,
    const float* __restrict__ bias, int mode, float* __restrict__ outf,
    u16* __restrict__ oh, u16* __restrict__ om, u16* __restrict__ ol,
    const float* __restrict__ resid, const float* __restrict__ xv,
    const float* __restrict__ embw, const float* __restrict__ embb,
    int ng, int bz, int biasz, long oz) {
    __shared__ __attribute__((aligned(16))) u16 AhL[16 * 264];
    __shared__ __attribute__((aligned(16))) u16 AmL[16 * 264];
    __shared__ __attribute__((aligned(16))) u16 AlL[16 * 264];
    int t = threadIdx.x;
    int w = t >> 6, l = t & 63;
    int lo16 = l & 15, q = l >> 4;
    int zi = blockIdx.z;
    const u16* bh = Bh_ + (size_t)zi * bz;
    const u16* bm = Bm_ + (size_t)zi * bz;
    const u16* bl = Bl_ + (size_t)zi * bz;
    int m0 = blockIdx.x * 16;
#pragma unroll
    for (int j = 0; j < 2; ++j) {
        int idx = t + j * 256;
        int r = idx >> 5, p = idx & 31;
        size_t goff = (size_t)(m0 + r) * 256 + p * 8;
        int loff = r * 264 + p * 8;
        *(short8*)&AhL[loff] = *(const short8*)&Ah[goff];
        *(short8*)&AmL[loff] = *(const short8*)&Am[goff];
        *(short8*)&AlL[loff] = *(const short8*)&Al[goff];
    }
    __syncthreads();
    for (int g = 0; g < ng; ++g) {
        int ncol = g * 64 + w * 16 + lo16;
        short8 Brh[8], Brm[8], Brl[8];
#pragma unroll
        for (int ks = 0; ks < 8; ++ks) {
            size_t boff = (size_t)ncol * 256 + ks * 32 + q * 8;
            Brh[ks] = *(const short8*)&bh[boff];
            Brm[ks] = *(const short8*)&bm[boff];
            Brl[ks] = *(const short8*)&bl[boff];
        }
        float bv = bias ? bias[biasz * zi + ncol] : 0.f;
        f32x4 acc = {0.f, 0.f, 0.f, 0.f};
#pragma unroll
        for (int ks = 0; ks < 8; ++ks) {
            int koff = ks * 32 + q * 8;
            short8 ah = *(const short8*)&AhL[lo16 * 264 + koff];
            short8 am = *(const short8*)&AmL[lo16 * 264 + koff];
            short8 al = *(const short8*)&AlL[lo16 * 264 + koff];
            acc = __builtin_amdgcn_mfma_f32_16x16x32_bf16(ah, Brh[ks], acc, 0, 0, 0);
            acc = __builtin_amdgcn_mfma_f32_16x16x32_bf16(ah, Brm[ks], acc, 0, 0, 0);
            acc = __builtin_amdgcn_mfma_f32_16x16x32_bf16(am, Brh[ks], acc, 0, 0, 0);
            acc = __builtin_amdgcn_mfma_f32_16x16x32_bf16(ah, Brl[ks], acc, 0, 0, 0);
            acc = __builtin_amdgcn_mfma_f32_16x16x32_bf16(am, Brm[ks], acc, 0, 0, 0);
            acc = __builtin_amdgcn_mfma_f32_16x16x32_bf16(al, Brh[ks], acc, 0, 0, 0);
        }
        float freq = 0.f;
        if (mode == MODE_FP) freq = expf(-(float)(ncol & ~1) * (logf(10000.f) / 256.f));
#pragma unroll
        for (int r = 0; r < 4; ++r) {
            int row = m0 + q * 4 + r;
            float v = acc[r] + bv;
            size_t o = (size_t)row * 256 + ncol;
            if (mode == MODE_FP) {
                int li = row & (LSEQ - 1);
                float ang = (float)li * freq;
                float pe = (ncol & 1) ? cosf(ang) : sinf(ang);
                v += xv[row] * embw[ncol] + embb[ncol] + pe;
                outf[o] = v;
            } else if (mode == MODE_UZ) {
                if (ncol < 256) {
                    v = v / (1.f + __expf(-v));
                    split3(v, oh[o], om[o], ol[o]);
                } else {
                    outf[(size_t)row * 256 + ncol - 256] = v;
                }
            } else if (mode == MODE_DT) {
                v = (v > 20.f) ? v : log1pf(__expf(v));
                outf[(size_t)zi * oz + o] = v;
            } else if (mode == MODE_BC) {
                outf[(size_t)row * 64 + ncol] = v;
            } else {
                v += resid[o];
                outf[o] = v;
            }
        }
    }
}

// ---------------- MFMA conv v2: one A-stage (18 rows incl halo), loop 4 col-groups x 3 taps ----------------
template <int CI, int KS>
__global__ __launch_bounds__(256, 2) void conv_mfma_k(
    const u16* __restrict__ Ah, const u16* __restrict__ Am, const u16* __restrict__ Al,
    const u16* __restrict__ Wh, const u16* __restrict__ Wm, const u16* __restrict__ Wl,
    const float* __restrict__ cb, const float* __restrict__ bg, const float* __restrict__ bb,
    u16* __restrict__ oh, u16* __restrict__ om, u16* __restrict__ ol) {
    const int STR = CI + 8;
    __shared__ __attribute__((aligned(16))) u16 AhL[18 * STR];
    __shared__ __attribute__((aligned(16))) u16 AmL[18 * STR];
    __shared__ __attribute__((aligned(16))) u16 AlL[18 * STR];
    int t = threadIdx.x, w = t >> 6, l = t & 63;
    int lo16 = l & 15, q = l >> 4;
    int m0 = blockIdx.x * 16;
    const int PARTS = CI / 8;
    for (int idx = t; idx < 18 * PARTS; idx += 256) {
        int r = idx / PARTS, p = idx - r * PARTS;
        long goff = (long)(m0 - 1 + r) * CI + p * 8;
        int loff = r * STR + p * 8;
        *(short8*)&AhL[loff] = *(const short8*)(Ah + goff);
        *(short8*)&AmL[loff] = *(const short8*)(Am + goff);
        *(short8*)&AlL[loff] = *(const short8*)(Al + goff);
    }
    __syncthreads();
    for (int g = 0; g < 4; ++g) {
        int ncol = g * 64 + w * 16 + lo16;
        float cbv = cb[ncol], gv = bg[ncol], bbv = bb[ncol];
        f32x4 acc = {0.f, 0.f, 0.f, 0.f};
#pragma unroll
        for (int tap = 0; tap < 3; ++tap) {
            short8 Brh[KS], Brm[KS], Brl[KS];
#pragma unroll
            for (int ks = 0; ks < KS; ++ks) {
                size_t boff = ((size_t)(tap * 256) + ncol) * CI + ks * 32 + q * 8;
                Brh[ks] = *(const short8*)&Wh[boff];
                Brm[ks] = *(const short8*)&Wm[boff];
                Brl[ks] = *(const short8*)&Wl[boff];
            }
#pragma unroll
            for (int ks = 0; ks < KS; ++ks) {
                int koff = ks * 32 + q * 8;
                int r0 = (lo16 + tap) * STR + koff;
                short8 ah = *(const short8*)&AhL[r0];
                short8 am = *(const short8*)&AmL[r0];
                short8 al = *(const short8*)&AlL[r0];
                acc = __builtin_amdgcn_mfma_f32_16x16x32_bf16(ah, Brh[ks], acc, 0, 0, 0);
                acc = __builtin_amdgcn_mfma_f32_16x16x32_bf16(ah, Brm[ks], acc, 0, 0, 0);
                acc = __builtin_amdgcn_mfma_f32_16x16x32_bf16(am, Brh[ks], acc, 0, 0, 0);
                acc = __builtin_amdgcn_mfma_f32_16x16x32_bf16(ah, Brl[ks], acc, 0, 0, 0);
                acc = __builtin_amdgcn_mfma_f32_16x16x32_bf16(am, Brm[ks], acc, 0, 0, 0);
                acc = __builtin_amdgcn_mfma_f32_16x16x32_bf16(al, Brh[ks], acc, 0, 0, 0);
            }
        }
#pragma unroll
        for (int r = 0; r < 4; ++r) {
            int row = m0 + q * 4 + r;
            float v = fmaxf(gv * (acc[r] + cbv) + bbv, 0.f);
            size_t o = (size_t)row * 256 + ncol;
            split3(v, oh[o], om[o], ol[o]);
        }
    }
}

// ---------------- conv boundary fixup: wave-per-co recompute of rows l=0 and l=2047 ----------------
template <int CI>
__global__ __launch_bounds__(256) void convfix_k(const u16* __restrict__ inh, const u16* __restrict__ inm,
                                                 const u16* __restrict__ inl, const u16* __restrict__ wh,
                                                 const u16* __restrict__ wm, const u16* __restrict__ wl,
                                                 const float* __restrict__ cb, const float* __restrict__ bg,
                                                 const float* __restrict__ bb, u16* __restrict__ oh,
                                                 u16* __restrict__ om, u16* __restrict__ ol) {
    int b = blockIdx.x, side = blockIdx.y;
    int w = threadIdx.x >> 6, lane = threadIdx.x & 63;
    int co = blockIdx.z * 4 + w;
    int l = side ? (LSEQ - 1) : 0;
    int tap0 = side ? 0 : 1;
    float acc = 0.f;
#pragma unroll
    for (int tp = 0; tp < 2; ++tp) {
        int tap = tap0 + tp;
        int li = l + tap - 1;
        size_t ibase = ((size_t)b * LSEQ + li) * CI;
        size_t wbase = ((size_t)(tap * 256) + co) * CI;
        for (int ci = lane; ci < CI; ci += 64)
            acc += rc3(inh, inm, inl, ibase + ci) * rc3(wh, wm, wl, wbase + ci);
    }
    for (int off = 32; off; off >>= 1) acc += __shfl_xor(acc, off, 64);
    if (lane == 0) {
        float v = fmaxf(bg[co] * (acc + cb[co]) + bb[co], 0.f);
        size_t o = ((size_t)b * LSEQ + l) * 256 + co;
        split3(v, oh[o], om[o], ol[o]);
    }
}

// ---------------- LayerNorm, wave-per-row -> split planes ----------------
__global__ __launch_bounds__(256) void ln_k(const float* __restrict__ xin, const float* __restrict__ g,
                                            const float* __restrict__ b, u16* __restrict__ oh,
                                            u16* __restrict__ om, u16* __restrict__ ol) {
    int t = threadIdx.x;
    int w = t >> 6, lane = t & 63;
    size_t row = (size_t)blockIdx.x * 4 + w;
    float4 v = *(const float4*)&xin[row * 256 + lane * 4];
    float s = v.x + v.y + v.z + v.w;
    float qq = v.x * v.x + v.y * v.y + v.z * v.z + v.w * v.w;
    for (int off = 32; off; off >>= 1) {
        s += __shfl_xor(s, off, 64);
        qq += __shfl_xor(qq, off, 64);
    }
    float m = s * (1.f / 256.f);
    float var = qq * (1.f / 256.f) - m * m;
    float r = rsqrtf(var + 1e-5f);
    float4 gg = *(const float4*)&g[lane * 4];
    float4 bb4 = *(const float4*)&b[lane * 4];
    float o0 = (v.x - m) * r * gg.x + bb4.x;
    float o1 = (v.y - m) * r * gg.y + bb4.y;
    float o2 = (v.z - m) * r * gg.z + bb4.z;
    float o3 = (v.w - m) * r * gg.w + bb4.w;
    u16 h[4], mm[4], ll[4];
    split3(o0, h[0], mm[0], ll[0]);
    split3(o1, h[1], mm[1], ll[1]);
    split3(o2, h[2], mm[2], ll[2]);
    split3(o3, h[3], mm[3], ll[3]);
    size_t i = row * 256 + lane * 4;
    uint2 p;
    p.x = (u32)h[0] | ((u32)h[1] << 16); p.y = (u32)h[2] | ((u32)h[3] << 16);
    *(uint2*)&oh[i] = p;
    p.x = (u32)mm[0] | ((u32)mm[1] << 16); p.y = (u32)mm[2] | ((u32)mm[3] << 16);
    *(uint2*)&om[i] = p;
    p.x = (u32)ll[0] | ((u32)ll[1] << 16); p.y = (u32)ll[2] | ((u32)ll[3] << 16);
    *(uint2*)&ol[i] = p;
}

// ---------------- chunked scan pass 1: 4 states/thread, 64 d per block ----------------
__global__ __launch_bounds__(256) void scan1_k(const float* __restrict__ dtbuf, const u16* __restrict__ uh,
                                               const u16* __restrict__ um, const u16* __restrict__ ul,
                                               const float* __restrict__ bc, const float* __restrict__ A_log,
                                               float* __restrict__ stA, float* __restrict__ stB) {
    int c = blockIdx.x, dgq = blockIdx.y;
    int b = blockIdx.z >> 1, dir = blockIdx.z & 1;
    int t = threadIdx.x;
    int dl = t >> 2, ng = t & 3;
    int d = dgq * 64 + dl;
    float4 Alv = *(const float4*)&A_log[(dir * 256 + d) * 16 + ng * 4];
    float Ac0 = -__expf(Alv.x), Ac1 = -__expf(Alv.y), Ac2 = -__expf(Alv.z), Ac3 = -__expf(Alv.w);
    const float* dtp = dtbuf + (size_t)dir * SZ;
    __shared__ __attribute__((aligned(16))) float s_dt[CT * 68];
    __shared__ __attribute__((aligned(16))) float s_u[CT * 68];
    __shared__ __attribute__((aligned(16))) float s_bu[CT * 20];
#pragma unroll
    for (int rep = 0; rep < 2; ++rep) {
        int idx = t + rep * 256;
        int i = idx >> 4, seg = idx & 15;
        int sq = c * CT + i;
        int tt = dir ? (LSEQ - 1 - sq) : sq;
        size_t rowoff = ((size_t)b * LSEQ + tt) * 256 + dgq * 64 + seg * 4;
        *(float4*)&s_dt[i * 68 + seg * 4] = *(const float4*)&dtp[rowoff];
        uint2 hh = *(const uint2*)&uh[rowoff], mm = *(const uint2*)&um[rowoff], ll = *(const uint2*)&ul[rowoff];
        float4 vv;
        vv.x = b2f(hh.x << 16) + b2f(mm.x << 16) + b2f(ll.x << 16);
        vv.y = b2f(hh.x & 0xFFFF0000u) + b2f(mm.x & 0xFFFF0000u) + b2f(ll.x & 0xFFFF0000u);
        vv.z = b2f(hh.y << 16) + b2f(mm.y << 16) + b2f(ll.y << 16);
        vv.w = b2f(hh.y & 0xFFFF0000u) + b2f(mm.y & 0xFFFF0000u) + b2f(ll.y & 0xFFFF0000u);
        *(float4*)&s_u[i * 68 + seg * 4] = vv;
    }
    if (t < 128) {
        int i = t >> 2, seg = t & 3;
        int sq = c * CT + i;
        int tt = dir ? (LSEQ - 1 - sq) : sq;
        *(float4*)&s_bu[i * 20 + seg * 4] = *(const float4*)&bc[((size_t)b * LSEQ + tt) * 64 + dir * 32 + seg * 4];
    }
    __syncthreads();
    float h0 = 0.f, h1 = 0.f, h2 = 0.f, h3 = 0.f;
    float A0 = 1.f, A1 = 1.f, A2 = 1.f, A3 = 1.f;
#pragma unroll
    for (int i = 0; i < CT; ++i) {
        float dtv = s_dt[i * 68 + dl];
        float uv = s_u[i * 68 + dl];
        float4 bu = *(const float4*)&s_bu[i * 20 + ng * 4];
        float du = dtv * uv;
        float a0 = __expf(dtv * Ac0), a1 = __expf(dtv * Ac1), a2 = __expf(dtv * Ac2), a3 = __expf(dtv * Ac3);
        A0 *= a0; A1 *= a1; A2 *= a2; A3 *= a3;
        h0 = a0 * h0 + du * bu.x;
        h1 = a1 * h1 + du * bu.y;
        h2 = a2 * h2 + du * bu.z;
        h3 = a3 * h3 + du * bu.w;
    }
    size_t o = ((size_t)(b * 2 + dir) * NCH + c) * 4096 + dgq * 1024 + dl * 16 + ng * 4;
    float4 av = {A0, A1, A2, A3};
    float4 hv = {h0, h1, h2, h3};
    *(float4*)&stA[o] = av;
    *(float4*)&stB[o] = hv;
}

// ---------------- chunked scan pass 2 (state layout d*16+n, unchanged) ----------------
__global__ __launch_bounds__(256) void scan2_k(const float* __restrict__ stA, const float* __restrict__ stB,
                                               float* __restrict__ stH) {
    int g = blockIdx.x * 256 + threadIdx.x;
    int bd = g >> 12;
    int idx = g & 4095;
    size_t base = (size_t)bd * NCH * 4096 + idx;
    float h = 0.f;
#pragma unroll 8
    for (int c = 0; c < NCH; ++c) {
        stH[base + (size_t)c * 4096] = h;
        h = stA[base + (size_t)c * 4096] * h + stB[base + (size_t)c * 4096];
    }
}

// ---------------- chunked scan pass 3: seeded recompute + 4-wide dot + 2-shuffle reduce ----------------
__global__ __launch_bounds__(256) void scan3_k(const float* __restrict__ dtbuf, const u16* __restrict__ uh,
                                               const u16* __restrict__ um, const u16* __restrict__ ul,
                                               const float* __restrict__ bc, const float* __restrict__ A_log,
                                               const float* __restrict__ Dp, const float* __restrict__ stH,
                                               float* __restrict__ y0, float* __restrict__ y1) {
    int c = blockIdx.x, dgq = blockIdx.y;
    int b = blockIdx.z >> 1, dir = blockIdx.z & 1;
    int t = threadIdx.x;
    int dl = t >> 2, ng = t & 3;
    int d = dgq * 64 + dl;
    float4 Alv = *(const float4*)&A_log[(dir * 256 + d) * 16 + ng * 4];
    float Ac0 = -__expf(Alv.x), Ac1 = -__expf(Alv.y), Ac2 = -__expf(Alv.z), Ac3 = -__expf(Alv.w);
    float Dv = Dp[dir * 256 + d];
    const float* dtp = dtbuf + (size_t)dir * SZ;
    float* yout = dir ? y1 : y0;
    __shared__ __attribute__((aligned(16))) float s_dt[CT * 68];
    __shared__ __attribute__((aligned(16))) float s_u[CT * 68];
    __shared__ __attribute__((aligned(16))) float s_bc[CT * 36];
#pragma unroll
    for (int rep = 0; rep < 2; ++rep) {
        int idx = t + rep * 256;
        int i = idx >> 4, seg = idx & 15;
        int sq = c * CT + i;
        int tt = dir ? (LSEQ - 1 - sq) : sq;
        size_t rowoff = ((size_t)b * LSEQ + tt) * 256 + dgq * 64 + seg * 4;
        *(float4*)&s_dt[i * 68 + seg * 4] = *(const float4*)&dtp[rowoff];
        uint2 hh = *(const uint2*)&uh[rowoff], mm = *(const uint2*)&um[rowoff], ll = *(const uint2*)&ul[rowoff];
        float4 vv;
        vv.x = b2f(hh.x << 16) + b2f(mm.x << 16) + b2f(ll.x << 16);
        vv.y = b2f(hh.x & 0xFFFF0000u) + b2f(mm.x & 0xFFFF0000u) + b2f(ll.x & 0xFFFF0000u);
        vv.z = b2f(hh.y << 16) + b2f(mm.y << 16) + b2f(ll.y << 16);
        vv.w = b2f(hh.y & 0xFFFF0000u) + b2f(mm.y & 0xFFFF0000u) + b2f(ll.y & 0xFFFF0000u);
        *(float4*)&s_u[i * 68 + seg * 4] = vv;
    }
    {
        int i = t >> 3, seg = t & 7;
        int sq = c * CT + i;
        int tt = dir ? (LSEQ - 1 - sq) : sq;
        *(float4*)&s_bc[i * 36 + seg * 4] = *(const float4*)&bc[((size_t)b * LSEQ + tt) * 64 + dir * 32 + seg * 4];
    }
    __syncthreads();
    size_t o = ((size_t)(b * 2 + dir) * NCH + c) * 4096 + dgq * 1024 + dl * 16 + ng * 4;
    float4 hv = *(const float4*)&stH[o];
    float h0 = hv.x, h1 = hv.y, h2 = hv.z, h3 = hv.w;
    int base_sq = c * CT;
#pragma unroll
    for (int i = 0; i < CT; ++i) {
        float dtv = s_dt[i * 68 + dl];
        float uv = s_u[i * 68 + dl];
        float4 bu = *(const float4*)&s_bc[i * 36 + ng * 4];
        float4 cv = *(const float4*)&s_bc[i * 36 + 16 + ng * 4];
        float du = dtv * uv;
        float a0 = __expf(dtv * Ac0), a1 = __expf(dtv * Ac1), a2 = __expf(dtv * Ac2), a3 = __expf(dtv * Ac3);
        h0 = a0 * h0 + du * bu.x;
        h1 = a1 * h1 + du * bu.y;
        h2 = a2 * h2 + du * bu.z;
        h3 = a3 * h3 + du * bu.w;
        float p = h0 * cv.x + h1 * cv.y + h2 * cv.z + h3 * cv.w;
        p += __shfl_xor(p, 1, 64);
        p += __shfl_xor(p, 2, 64);
        if (ng == 0) {
            int sq = base_sq + i;
            int tt = dir ? (LSEQ - 1 - sq) : sq;
            yout[((size_t)b * LSEQ + tt) * 256 + d] = p + uv * Dv;
        }
    }
}

// ---------------- gate -> split planes ----------------
__global__ __launch_bounds__(256) void gate_k(const float* __restrict__ y0, const float* __restrict__ y1,
                                              const float* __restrict__ z, u16* __restrict__ gh,
                                              u16* __restrict__ gm, u16* __restrict__ gl) {
    size_t i = (size_t)blockIdx.x * 256 + threadIdx.x;
    float4 v0 = ((const float4*)y0)[i];
    float4 v1 = ((const float4*)y1)[i];
    float4 vz = ((const float4*)z)[i];
    float g0 = (v0.x + v1.x) * (vz.x / (1.f + __expf(-vz.x)));
    float g1 = (v0.y + v1.y) * (vz.y / (1.f + __expf(-vz.y)));
    float g2 = (v0.z + v1.z) * (vz.z / (1.f + __expf(-vz.z)));
    float g3 = (v0.w + v1.w) * (vz.w / (1.f + __expf(-vz.w)));
    u16 h[4], m[4], l[4];
    split3(g0, h[0], m[0], l[0]);
    split3(g1, h[1], m[1], l[1]);
    split3(g2, h[2], m[2], l[2]);
    split3(g3, h[3], m[3], l[3]);
    uint2 p;
    p.x = (u32)h[0] | ((u32)h[1] << 16); p.y = (u32)h[2] | ((u32)h[3] << 16);
    *(uint2*)&gh[i * 4] = p;
    p.x = (u32)m[0] | ((u32)m[1] << 16); p.y = (u32)m[2] | ((u32)m[3] << 16);
    *(uint2*)&gm[i * 4] = p;
    p.x = (u32)l[0] | ((u32)l[1] << 16); p.y = (u32)l[2] | ((u32)l[3] << 16);
    *(uint2*)&gl[i * 4] = p;
}

// ---------------- means over L (two-stage); x_cnn from split planes ----------------
__global__ __launch_bounds__(256) void mean1_k(const u16* __restrict__ ch, const u16* __restrict__ cm,
                                               const u16* __restrict__ cl, const float* __restrict__ xm,
                                               float* __restrict__ part) {
    int b = blockIdx.x, chk = blockIdx.y, t = threadIdx.x;
    float s1 = 0.f, s2 = 0.f;
    for (int l = chk * 64; l < chk * 64 + 64; ++l) {
        size_t o = ((size_t)b * LSEQ + l) * 256 + t;
        s1 += rc3(ch, cm, cl, o);
        s2 += xm[o];
    }
    part[(b * 32 + chk) * 512 + t] = s1;
    part[(b * 32 + chk) * 512 + 256 + t] = s2;
}

__global__ __launch_bounds__(256) void mean2_k(const float* __restrict__ part, float* __restrict__ xflat) {
    int b = blockIdx.x, t = threadIdx.x;
    float s1 = 0.f, s2 = 0.f;
    for (int ch = 0; ch < 32; ++ch) {
        s1 += part[(b * 32 + ch) * 512 + t];
        s2 += part[(b * 32 + ch) * 512 + 256 + t];
    }
    xflat[b * 528 + t] = s1 * (1.f / 2048.f);
    xflat[b * 528 + 256 + t] = s2 * (1.f / 2048.f);
}

// ---------------- x_main two-stage ----------------
__global__ __launch_bounds__(256) void xmain1_k(const float* __restrict__ x, const float* __restrict__ w1,
                                                float* __restrict__ part2) {
    int b = blockIdx.x, ch = blockIdx.y, t = threadIdx.x;
    float acc = 0.f;
    for (int k = ch * 128; k < ch * 128 + 128; ++k) acc += x[b * LSEQ + k] * w1[k * 256 + t];
    part2[(b * 16 + ch) * 256 + t] = acc;
}

__global__ __launch_bounds__(256) void xmain2_k(const float* __restrict__ part2, const float* __restrict__ b1,
                                                const float* __restrict__ w2, const float* __restrict__ b2,
                                                float* __restrict__ xflat) {
    int b = blockIdx.x, t = threadIdx.x;
    float acc = b1[t];
    for (int ch = 0; ch < 16; ++ch) acc += part2[(b * 16 + ch) * 256 + t];
    __shared__ float h[256];
    h[t] = fmaxf(acc, 0.f);
    __syncthreads();
    if (t < 16) {
        float a2 = b2[t];
        for (int k = 0; k < 256; ++k) a2 += h[k] * w2[k * 16 + t];
        xflat[b * 528 + 512 + t] = a2;
    }
}

// ---------------- main_weights ----------------
__global__ void mew_k(const float* __restrict__ mew, float* __restrict__ outp) {
    int i = blockIdx.x * 256 + threadIdx.x;
    if (i < LSEQ) outp[4 + i] = 1.f / (1.f + __expf(-mew[i]));
}

// ---------------- pair scores ----------------
__global__ __launch_bounds__(256) void scores_k(const float* __restrict__ xm, const int* __restrict__ pairs,
                                                const float* __restrict__ epw, const float* __restrict__ epb,
                                                float* __restrict__ scores) {
    int p = blockIdx.x;
    int t = threadIdx.x;
    int w = t >> 6, lane = t & 63;
    int pi = pairs[2 * p], pj = pairs[2 * p + 1];
    float acc = 0.f;
    for (int c = lane; c < 256; c += 64) {
        acc += xm[((size_t)w * LSEQ + pi) * 256 + c] * epw[c];
        acc += xm[((size_t)w * LSEQ + pj) * 256 + c] * epw[256 + c];
    }
    for (int off = 32; off; off >>= 1) acc += __shfl_xor(acc, off, 64);
    __shared__ float sb[4];
    if (lane == 0) sb[w] = 1.f / (1.f + __expf(-(acc + epb[0])));
    __syncthreads();
    if (t == 0) scores[p] = 0.25f * (sb[0] + sb[1] + sb[2] + sb[3]);
}

// ---------------- top-k (full stable rank of 200) ----------------
__global__ __launch_bounds__(256) void topk_k(const float* __restrict__ scores, const int* __restrict__ pairs,
                                              float* __restrict__ outp) {
    __shared__ float s[200];
    int t = threadIdx.x;
    if (t < 200) s[t] = scores[t];
    __syncthreads();
    if (t < 200) {
        float v = s[t];
        int r = 0;
        for (int q = 0; q < 200; ++q) {
            float u = s[q];
            r += (u > v) || (u == v && q < t);
        }
        outp[2052 + 2 * r] = (float)pairs[2 * t];
        outp[2052 + 2 * r + 1] = (float)pairs[2 * t + 1];
        outp[2452 + r] = v;
    }
}

// ---------------- epi MLP + out head ----------------
__global__ __launch_bounds__(128) void epi_k(const float* __restrict__ xflat, const float* __restrict__ w1,
                                             const float* __restrict__ b1, const float* __restrict__ w2,
                                             const float* __restrict__ b2, const float* __restrict__ w3,
                                             const float* __restrict__ b3, const float* __restrict__ ow1,
                                             const float* __restrict__ ob1, const float* __restrict__ ow2,
                                             const float* __restrict__ ob2, float* __restrict__ outp) {
    int b = blockIdx.x, t = threadIdx.x;
    __shared__ float xb[528], e1[128], e2[64], e3[32], o1[16];
    for (int idx = t; idx < 528; idx += 128) xb[idx] = xflat[b * 528 + idx];
    __syncthreads();
    {
        float a = b1[t];
        for (int k = 0; k < 528; ++k) a += xb[k] * w1[k * 128 + t];
        e1[t] = fmaxf(a, 0.f);
    }
    __syncthreads();
    if (t < 64) {
        float a = b2[t];
        for (int k = 0; k < 128; ++k) a += e1[k] * w2[k * 64 + t];
        e2[t] = fmaxf(a, 0.f);
    }
    __syncthreads();
    if (t < 32) {
        float a = b3[t];
        for (int k = 0; k < 64; ++k) a += e2[k] * w3[k * 32 + t];
        e3[t] = a;
    }
    __syncthreads();
    if (t < 16) {
        float a = ob1[t];
        for (int k = 0; k < 32; ++k) a += e3[k] * ow1[k * 16 + t];
        o1[t] = fmaxf(a, 0.f);
    }
    __syncthreads();
    if (t == 0) {
        float a = ob2[0];
        for (int k = 0; k < 16; ++k) a += o1[k] * ow2[k];
        outp[b] = 1.f / (1.f + __expf(-a));
    }
}

extern "C" void kernel_launch(void* const* d_in, const int* in_sizes, int n_in, void* d_out, int out_size,
                              void* d_ws, size_t ws_size, hipStream_t stream) {
    (void)in_sizes; (void)n_in; (void)out_size; (void)ws_size;
    const float* x = (const float*)d_in[0];
    const int* pairs = (const int*)d_in[1];
    const float* emb_w = (const float*)d_in[2];
    const float* emb_b = (const float*)d_in[3];
    const float* conv0_w = (const float*)d_in[4];
    const float* conv0_b = (const float*)d_in[5];
    const float* bn0_g = (const float*)d_in[6];
    const float* bn0_b = (const float*)d_in[7];
    const float* conv1_w = (const float*)d_in[8];
    const float* conv1_b = (const float*)d_in[9];
    const float* bn1_g = (const float*)d_in[10];
    const float* bn1_b = (const float*)d_in[11];
    const float* conv2_w = (const float*)d_in[12];
    const float* conv2_b = (const float*)d_in[13];
    const float* bn2_g = (const float*)d_in[14];
    const float* bn2_b = (const float*)d_in[15];
    const float* conv3_w = (const float*)d_in[16];
    const float* conv3_b = (const float*)d_in[17];
    const float* bn3_g = (const float*)d_in[18];
    const float* bn3_b = (const float*)d_in[19];
    const float* fp_w = (const float*)d_in[20];
    const float* fp_b = (const float*)d_in[21];
    const float* mb_norm_g = (const float*)d_in[22];
    const float* mb_norm_b = (const float*)d_in[23];
    const float* mb_in_w = (const float*)d_in[24];
    const float* mb_in_b = (const float*)d_in[25];
    const float* mb_A_log = (const float*)d_in[26];
    const float* mb_dt_w = (const float*)d_in[27];
    const float* mb_dt_b = (const float*)d_in[28];
    const float* mb_B_w = (const float*)d_in[29];
    const float* mb_C_w = (const float*)d_in[30];
    const float* mb_D = (const float*)d_in[31];
    const float* mb_out_w = (const float*)d_in[32];
    const float* mb_out_b = (const float*)d_in[33];
    const float* me_w1 = (const float*)d_in[34];
    const float* me_b1 = (const float*)d_in[35];
    const float* me_w2 = (const float*)d_in[36];
    const float* me_b2 = (const float*)d_in[37];
    const float* mew = (const float*)d_in[38];
    const float* ep_w = (const float*)d_in[39];
    const float* ep_b = (const float*)d_in[40];
    const float* epi_w1 = (const float*)d_in[41];
    const float* epi_b1 = (const float*)d_in[42];
    const float* epi_w2 = (const float*)d_in[43];
    const float* epi_b2 = (const float*)d_in[44];
    const float* epi_w3 = (const float*)d_in[45];
    const float* epi_b3 = (const float*)d_in[46];
    const float* out_w1 = (const float*)d_in[47];
    const float* out_b1 = (const float*)d_in[48];
    const float* out_w2 = (const float*)d_in[49];
    const float* out_b2 = (const float*)d_in[50];
    float* outp = (float*)d_out;

    float* ws = (float*)d_ws;
    size_t off = 0;
    auto AL = [&](size_t n) { float* p = ws + off; off += n; return p; };
    float* xm = AL(SZ);
    float* z = AL(SZ);
    float* dtb = AL(2 * SZ); // c0 split planes aliased inside (dead before dt written)
    float* y0 = AL(SZ);      // stA alias
    float* y1 = AL(SZ);      // stB alias
    float* bcb = AL(SZ / 4);
    AL(128);
    float* c1s = AL(SZ + SZ / 2); // 3 planes x SZ u16 ; also ln/gate splits + stH alias
    AL(128);
    float* c2s = AL(SZ + SZ / 2); // also u split planes
    AL(128);
    float* c3s = AL(SZ + SZ / 2);
    AL(128);
    float* wfp = AL(98304);
    float* win = AL(393216);
    float* wdt = AL(393216);
    float* wou = AL(196608);
    float* wc1 = AL(147456);
    float* wc2 = AL(294912);
    float* wc3 = AL(294912);
    float* wbc = AL(49152);
    float* part = AL(65536);
    float* part2 = AL(16384);
    float* xflat = AL(2112);
    float* scoresb = AL(256);

    u16* c0h = (u16*)dtb + 128;
    u16* c0m = c0h + SZ / 2;
    u16* c0l = c0m + SZ / 2;
    u16* c1h = (u16*)c1s; u16* c1m = c1h + SZ; u16* c1l = c1m + SZ;
    u16* c2h = (u16*)c2s; u16* c2m = c2h + SZ; u16* c2l = c2m + SZ;
    u16* c3h = (u16*)c3s; u16* c3m = c3h + SZ; u16* c3l = c3m + SZ;
    float* stH = c1s;
    u16* wfph = (u16*)wfp; u16* wfpm = wfph + 65536; u16* wfpl = wfpm + 65536;
    u16* winh = (u16*)win; u16* winm = winh + 262144; u16* winl = winm + 262144;
    u16* wdth = (u16*)wdt; u16* wdtm = wdth + 262144; u16* wdtl = wdtm + 262144;
    u16* wouh = (u16*)wou; u16* woum = wouh + 131072; u16* woul = woum + 131072;
    u16* wc1h = (u16*)wc1; u16* wc1m = wc1h + 98304; u16* wc1l = wc1m + 98304;
    u16* wc2h = (u16*)wc2; u16* wc2m = wc2h + 196608; u16* wc2l = wc2m + 196608;
    u16* wc3h = (u16*)wc3; u16* wc3m = wc3h + 196608; u16* wc3l = wc3m + 196608;
    u16* wbch = (u16*)wbc; u16* wbcm = wbch + 32768; u16* wbcl = wbcm + 32768;

    // weight prep
    wsplit_t<<<256, 256, 0, stream>>>(fp_w, 256, 256, 65536, wfph, wfpm, wfpl);
    wsplit_t<<<1024, 256, 0, stream>>>(mb_in_w, 256, 512, 262144, winh, winm, winl);
    wsplit_t<<<1024, 256, 0, stream>>>(mb_dt_w, 256, 256, 262144, wdth, wdtm, wdtl);
    wsplit_t<<<512, 256, 0, stream>>>(mb_out_w, 256, 256, 131072, wouh, woum, woul);
    wsplit_conv<<<384, 256, 0, stream>>>(conv1_w, 128, 98304, wc1h, wc1m, wc1l);
    wsplit_conv<<<768, 256, 0, stream>>>(conv2_w, 256, 196608, wc2h, wc2m, wc2l);
    wsplit_conv<<<768, 256, 0, stream>>>(conv3_w, 256, 196608, wc3h, wc3m, wc3l);
    wsplit_bc<<<128, 256, 0, stream>>>(mb_B_w, mb_C_w, wbch, wbcm, wbcl);

    // CNN
    conv0_k<<<4096, 256, 0, stream>>>(x, conv0_w, conv0_b, bn0_g, bn0_b, c0h, c0m, c0l);
    conv_mfma_k<128, 4><<<512, 256, 0, stream>>>(c0h, c0m, c0l, wc1h, wc1m, wc1l, conv1_b, bn1_g, bn1_b,
                                                 c1h, c1m, c1l);
    convfix_k<128><<<dim3(4, 2, 64), 256, 0, stream>>>(c0h, c0m, c0l, wc1h, wc1m, wc1l, conv1_b, bn1_g, bn1_b,
                                                       c1h, c1m, c1l);
    conv_mfma_k<256, 8><<<512, 256, 0, stream>>>(c1h, c1m, c1l, wc2h, wc2m, wc2l, conv2_b, bn2_g, bn2_b,
                                                 c2h, c2m, c2l);
    convfix_k<256><<<dim3(4, 2, 64), 256, 0, stream>>>(c1h, c1m, c1l, wc2h, wc2m, wc2l, conv2_b, bn2_g, bn2_b,
                                                       c2h, c2m, c2l);
    conv_mfma_k<256, 8><<<512, 256, 0, stream>>>(c2h, c2m, c2l, wc3h, wc3m, wc3l, conv3_b, bn3_g, bn3_b,
                                                 c3h, c3m, c3l);
    convfix_k<256><<<dim3(4, 2, 64), 256, 0, stream>>>(c2h, c2m, c2l, wc3h, wc3m, wc3l, conv3_b, bn3_g, bn3_b,
                                                       c3h, c3m, c3l);

    // xm = x_embed + x_cnn@fp_w + fp_b + PE
    mfma_gemm_k<<<512, 256, 0, stream>>>(c3h, c3m, c3l, wfph, wfpm, wfpl, fp_b, MODE_FP, xm,
                                         nullptr, nullptr, nullptr, nullptr, x, emb_w, emb_b, 4, 0, 0, 0);

    for (int l = 0; l < 2; ++l) {
        ln_k<<<2048, 256, 0, stream>>>(xm, mb_norm_g + l * 256, mb_norm_b + l * 256, c1h, c1m, c1l);
        mfma_gemm_k<<<512, 256, 0, stream>>>(c1h, c1m, c1l, winh + l * 131072, winm + l * 131072,
                                             winl + l * 131072, mb_in_b + l * 512, MODE_UZ, z,
                                             c2h, c2m, c2l, nullptr, nullptr, nullptr, nullptr, 8, 0, 0, 0);
        mfma_gemm_k<<<dim3(512, 1, 2), 256, 0, stream>>>(c2h, c2m, c2l, wdth + 2 * l * 65536, wdtm + 2 * l * 65536,
                                                         wdtl + 2 * l * 65536, mb_dt_b + l * 512, MODE_DT, dtb,
                                                         nullptr, nullptr, nullptr, nullptr, nullptr, nullptr,
                                                         nullptr, 4, 65536, 256, (long)SZ);
        mfma_gemm_k<<<512, 256, 0, stream>>>(c2h, c2m, c2l, wbch + l * 16384, wbcm + l * 16384,
                                             wbcl + l * 16384, nullptr, MODE_BC, bcb,
                                             nullptr, nullptr, nullptr, nullptr, nullptr, nullptr,
                                             nullptr, 1, 0, 0, 0);
        scan1_k<<<dim3(NCH, 4, 8), 256, 0, stream>>>(dtb, c2h, c2m, c2l, bcb, mb_A_log + l * 8192, y0, y1);
        scan2_k<<<128, 256, 0, stream>>>(y0, y1, stH);
        scan3_k<<<dim3(NCH, 4, 8), 256, 0, stream>>>(dtb, c2h, c2m, c2l, bcb, mb_A_log + l * 8192, mb_D + l * 512,
                                                     stH, y0, y1);
        gate_k<<<2048, 256, 0, stream>>>(y0, y1, z, c1h, c1m, c1l);
        mfma_gemm_k<<<512, 256, 0, stream>>>(c1h, c1m, c1l, wouh + l * 65536, woum + l * 65536,
                                             woul + l * 65536, mb_out_b + l * 256, MODE_OUT, xm,
                                             nullptr, nullptr, nullptr, xm, nullptr, nullptr, nullptr,
                                             4, 0, 0, 0);
    }

    // heads
    mean1_k<<<dim3(4, 32), 256, 0, stream>>>(c3h, c3m, c3l, xm, part);
    mean2_k<<<4, 256, 0, stream>>>(part, xflat);
    xmain1_k<<<dim3(4, 16), 256, 0, stream>>>(x, me_w1, part2);
    xmain2_k<<<4, 256, 0, stream>>>(part2, me_b1, me_w2, me_b2, xflat);
    mew_k<<<8, 256, 0, stream>>>(mew, outp);
    scores_k<<<200, 256, 0, stream>>>(xm, pairs, ep_w, ep_b, scoresb);
    topk_k<<<1, 256, 0, stream>>>(scoresb, pairs, outp);
    epi_k<<<4, 128, 0, stream>>>(xflat, epi_w1, epi_b1, epi_w2, epi_b2, epi_w3, epi_b3, out_w1, out_b1, out_w2,
                                 out_b2, outp);
}

// Round 10
// 799.848 us; speedup vs baseline: 1.1797x; 1.1797x over previous
//
#include <hip/hip_runtime.h>
#include <math.h>

typedef unsigned short u16;
typedef unsigned int u32;
typedef __attribute__((ext_vector_type(8))) short short8;
typedef __attribute__((ext_vector_type(4))) float f32x4;

#define BB 4
#define LSEQ 2048
static const size_t SZ = (size_t)BB * LSEQ * 256; // 2097152

#define NCH 64
#define CT 32

__device__ __forceinline__ float b2f(u32 u) { return __uint_as_float(u); }

// 3-way bf16 split: x = h + m + l - eps, |eps| <= 2^-27 |x|
__device__ __forceinline__ void split3(float x, u16& h, u16& m, u16& l) {
    u32 xu = __float_as_uint(x);
    u32 hu = (xu + 0x7FFFu + ((xu >> 16) & 1u)) & 0xFFFF0000u;
    h = (u16)(hu >> 16);
    float r1 = x - b2f(hu);
    u32 r1u = __float_as_uint(r1);
    u32 mu = (r1u + 0x7FFFu + ((r1u >> 16) & 1u)) & 0xFFFF0000u;
    m = (u16)(mu >> 16);
    float r2 = r1 - b2f(mu);
    u32 lu = __float_as_uint(r2);
    l = (u16)((lu + 0x7FFFu + ((lu >> 16) & 1u)) >> 16);
}

__device__ __forceinline__ float rc3(const u16* __restrict__ h, const u16* __restrict__ m,
                                     const u16* __restrict__ l, size_t i) {
    return b2f((u32)h[i] << 16) + b2f((u32)m[i] << 16) + b2f((u32)l[i] << 16);
}

// ---------------- weight transpose+split: W[mat][K][N] -> planes [mat][n][k] ----------------
__global__ void wsplit_t(const float* __restrict__ W, int Kd, int Nd, int total,
                         u16* __restrict__ oh, u16* __restrict__ om, u16* __restrict__ ol) {
    int idx = blockIdx.x * 256 + threadIdx.x;
    if (idx >= total) return;
    int per = Kd * Nd;
    int mat = idx / per;
    int r = idx - mat * per;
    int n = r / Kd;
    int k = r - n * Kd;
    float v = W[(size_t)mat * per + (size_t)k * Nd + n];
    split3(v, oh[idx], om[idx], ol[idx]);
}

// ---------------- conv weight split: w[co][ci][3] -> planes [tap][co][ci] ----------------
__global__ void wsplit_conv(const float* __restrict__ w, int CI, int total,
                            u16* __restrict__ oh, u16* __restrict__ om, u16* __restrict__ ol) {
    int idx = blockIdx.x * 256 + threadIdx.x;
    if (idx >= total) return;
    int ci = idx % CI;
    int tmp = idx / CI;
    int co = tmp & 255;
    int tap = tmp >> 8;
    float v = w[(co * CI + ci) * 3 + tap];
    split3(v, oh[idx], om[idx], ol[idx]);
}

// ---------------- B/C weight split for bcproj GEMM: [layer][n(64)][k(256)] ----------------
__global__ void wsplit_bc(const float* __restrict__ Bw, const float* __restrict__ Cw,
                          u16* __restrict__ oh, u16* __restrict__ om, u16* __restrict__ ol) {
    int idx = blockIdx.x * 256 + threadIdx.x; // 32768 total
    int layer = idx >> 14;
    int r = idx & 16383;
    int n = r >> 8, k = r & 255;
    int dir = n >> 5, which = (n >> 4) & 1, col = n & 15;
    const float* src = which ? Cw : Bw;
    float v = src[layer * 8192 + dir * 4096 + k * 16 + col];
    split3(v, oh[idx], om[idx], ol[idx]);
}

// ---------------- conv0: Ci=1, Co=128 -> split planes (B,L,128) ----------------
__global__ __launch_bounds__(256) void conv0_k(const float* __restrict__ x, const float* __restrict__ w,
                                               const float* __restrict__ cb, const float* __restrict__ g,
                                               const float* __restrict__ bb, u16* __restrict__ oh,
                                               u16* __restrict__ om, u16* __restrict__ ol) {
    int gid = blockIdx.x * 256 + threadIdx.x;
    int co = gid & 127;
    int l = (gid >> 7) & (LSEQ - 1);
    int b = gid >> 18;
    const float* xr = x + (size_t)b * LSEQ;
    float xm1 = (l > 0) ? xr[l - 1] : 0.f;
    float x0 = xr[l];
    float xp1 = (l < LSEQ - 1) ? xr[l + 1] : 0.f;
    float v = xm1 * w[co * 3] + x0 * w[co * 3 + 1] + xp1 * w[co * 3 + 2] + cb[co];
    v = fmaxf(g[co] * v + bb[co], 0.f);
    size_t o = ((size_t)b * LSEQ + l) * 128 + co;
    split3(v, oh[o], om[o], ol[o]);
}

#define MODE_FP 0
#define MODE_UZ 1
#define MODE_DT 2
#define MODE_OUT 3
#define MODE_BC 4

// ---------------- MFMA GEMM (r7 structure, NT threads = NT/64 waves, NT/4 cols per block) ----------
// block: 64 rows (2 chunks of 32) x NT/4 cols; B in regs once per wave; A staged per chunk.
template <int NT>
__global__ __launch_bounds__(NT, (NT == 256) ? 2 : 4) void mfma_gemm_k(
    const u16* __restrict__ Ah, const u16* __restrict__ Am, const u16* __restrict__ Al,
    const u16* __restrict__ Bh_, const u16* __restrict__ Bm_, const u16* __restrict__ Bl_,
    const float* __restrict__ bias, int mode, float* __restrict__ outf,
    u16* __restrict__ oh, u16* __restrict__ om, u16* __restrict__ ol,
    const float* __restrict__ resid, const float* __restrict__ xv,
    const float* __restrict__ embw, const float* __restrict__ embb,
    int bz, int biasz, long oz) {
    __shared__ __attribute__((aligned(16))) u16 AhL[32 * 264];
    __shared__ __attribute__((aligned(16))) u16 AmL[32 * 264];
    __shared__ __attribute__((aligned(16))) u16 AlL[32 * 264];
    int t = threadIdx.x;
    int w = t >> 6, l = t & 63;
    int lo16 = l & 15, q = l >> 4;
    int zi = blockIdx.z;
    const u16* bh = Bh_ + (size_t)zi * bz;
    const u16* bm = Bm_ + (size_t)zi * bz;
    const u16* bl = Bl_ + (size_t)zi * bz;
    int ncol = blockIdx.y * (NT / 4) + w * 16 + lo16;
    short8 Brh[8], Brm[8], Brl[8];
#pragma unroll
    for (int ks = 0; ks < 8; ++ks) {
        size_t boff = (size_t)ncol * 256 + ks * 32 + q * 8;
        Brh[ks] = *(const short8*)&bh[boff];
        Brm[ks] = *(const short8*)&bm[boff];
        Brl[ks] = *(const short8*)&bl[boff];
    }
    float bv = bias ? bias[biasz * zi + ncol] : 0.f;
    int m_base = blockIdx.x * 64;
    for (int c = 0; c < 2; ++c) {
        int m0 = m_base + c * 32;
        if (c) __syncthreads();
#pragma unroll
        for (int idx = t; idx < 1024; idx += NT) {
            int r = idx >> 5, p = idx & 31;
            size_t goff = (size_t)(m0 + r) * 256 + p * 8;
            int loff = r * 264 + p * 8;
            *(short8*)&AhL[loff] = *(const short8*)&Ah[goff];
            *(short8*)&AmL[loff] = *(const short8*)&Am[goff];
            *(short8*)&AlL[loff] = *(const short8*)&Al[goff];
        }
        __syncthreads();
        f32x4 acc0 = {0.f, 0.f, 0.f, 0.f}, acc1 = {0.f, 0.f, 0.f, 0.f};
#pragma unroll
        for (int ks = 0; ks < 8; ++ks) {
            int koff = ks * 32 + q * 8;
            short8 a0h = *(const short8*)&AhL[lo16 * 264 + koff];
            short8 a0m = *(const short8*)&AmL[lo16 * 264 + koff];
            short8 a0l = *(const short8*)&AlL[lo16 * 264 + koff];
            short8 a1h = *(const short8*)&AhL[(16 + lo16) * 264 + koff];
            short8 a1m = *(const short8*)&AmL[(16 + lo16) * 264 + koff];
            short8 a1l = *(const short8*)&AlL[(16 + lo16) * 264 + koff];
            acc0 = __builtin_amdgcn_mfma_f32_16x16x32_bf16(a0h, Brh[ks], acc0, 0, 0, 0);
            acc0 = __builtin_amdgcn_mfma_f32_16x16x32_bf16(a0h, Brm[ks], acc0, 0, 0, 0);
            acc0 = __builtin_amdgcn_mfma_f32_16x16x32_bf16(a0m, Brh[ks], acc0, 0, 0, 0);
            acc0 = __builtin_amdgcn_mfma_f32_16x16x32_bf16(a0h, Brl[ks], acc0, 0, 0, 0);
            acc0 = __builtin_amdgcn_mfma_f32_16x16x32_bf16(a0m, Brm[ks], acc0, 0, 0, 0);
            acc0 = __builtin_amdgcn_mfma_f32_16x16x32_bf16(a0l, Brh[ks], acc0, 0, 0, 0);
            acc1 = __builtin_amdgcn_mfma_f32_16x16x32_bf16(a1h, Brh[ks], acc1, 0, 0, 0);
            acc1 = __builtin_amdgcn_mfma_f32_16x16x32_bf16(a1h, Brm[ks], acc1, 0, 0, 0);
            acc1 = __builtin_amdgcn_mfma_f32_16x16x32_bf16(a1m, Brh[ks], acc1, 0, 0, 0);
            acc1 = __builtin_amdgcn_mfma_f32_16x16x32_bf16(a1h, Brl[ks], acc1, 0, 0, 0);
            acc1 = __builtin_amdgcn_mfma_f32_16x16x32_bf16(a1m, Brm[ks], acc1, 0, 0, 0);
            acc1 = __builtin_amdgcn_mfma_f32_16x16x32_bf16(a1l, Brh[ks], acc1, 0, 0, 0);
        }
        float freq = 0.f;
        if (mode == MODE_FP) freq = expf(-(float)(ncol & ~1) * (logf(10000.f) / 256.f));
#pragma unroll
        for (int mt = 0; mt < 2; ++mt) {
            f32x4 a = mt ? acc1 : acc0;
#pragma unroll
            for (int r = 0; r < 4; ++r) {
                int row = m0 + mt * 16 + q * 4 + r;
                float v = a[r] + bv;
                size_t o = (size_t)row * 256 + ncol;
                if (mode == MODE_FP) {
                    int li = row & (LSEQ - 1);
                    float ang = (float)li * freq;
                    float pe = (ncol & 1) ? cosf(ang) : sinf(ang);
                    v += xv[row] * embw[ncol] + embb[ncol] + pe;
                    outf[o] = v;
                } else if (mode == MODE_UZ) {
                    if (ncol < 256) {
                        v = v / (1.f + __expf(-v));
                        split3(v, oh[o], om[o], ol[o]);
                    } else {
                        outf[(size_t)row * 256 + ncol - 256] = v;
                    }
                } else if (mode == MODE_DT) {
                    v = (v > 20.f) ? v : log1pf(__expf(v));
                    outf[(size_t)zi * oz + o] = v;
                } else if (mode == MODE_BC) {
                    outf[(size_t)row * 64 + ncol] = v;
                } else {
                    v += resid[o];
                    outf[o] = v;
                }
            }
        }
    }
}

// ---------------- MFMA conv (r7 structure, NT threads): implicit GEMM over 3 taps ----------------
template <int CI, int KS, int NT>
__global__ __launch_bounds__(NT, (NT == 256) ? 2 : 4) void conv_mfma_k(
    const u16* __restrict__ Ah, const u16* __restrict__ Am, const u16* __restrict__ Al,
    const u16* __restrict__ Wh, const u16* __restrict__ Wm, const u16* __restrict__ Wl,
    const float* __restrict__ cb, const float* __restrict__ bg, const float* __restrict__ bb,
    u16* __restrict__ oh, u16* __restrict__ om, u16* __restrict__ ol) {
    const int STR = CI + 8;
    __shared__ __attribute__((aligned(16))) u16 AhL[34 * STR];
    __shared__ __attribute__((aligned(16))) u16 AmL[34 * STR];
    __shared__ __attribute__((aligned(16))) u16 AlL[34 * STR];
    int t = threadIdx.x, w = t >> 6, l = t & 63;
    int lo16 = l & 15, q = l >> 4;
    int ncol = blockIdx.y * (NT / 4) + w * 16 + lo16;
    int m_base = blockIdx.x * 64;
    float cbv = cb[ncol], gv = bg[ncol], bbv = bb[ncol];
    for (int c = 0; c < 2; ++c) {
        int m0 = m_base + c * 32;
        if (c) __syncthreads();
        const int PARTS = CI / 8;
        for (int idx = t; idx < 34 * PARTS; idx += NT) {
            int r = idx / PARTS, p = idx - r * PARTS;
            long goff = (long)(m0 - 1 + r) * CI + p * 8;
            int loff = r * STR + p * 8;
            *(short8*)&AhL[loff] = *(const short8*)(Ah + goff);
            *(short8*)&AmL[loff] = *(const short8*)(Am + goff);
            *(short8*)&AlL[loff] = *(const short8*)(Al + goff);
        }
        __syncthreads();
        f32x4 acc0 = {0.f, 0.f, 0.f, 0.f}, acc1 = {0.f, 0.f, 0.f, 0.f};
#pragma unroll
        for (int tap = 0; tap < 3; ++tap) {
            short8 Brh[KS], Brm[KS], Brl[KS];
#pragma unroll
            for (int ks = 0; ks < KS; ++ks) {
                size_t boff = ((size_t)(tap * 256) + ncol) * CI + ks * 32 + q * 8;
                Brh[ks] = *(const short8*)&Wh[boff];
                Brm[ks] = *(const short8*)&Wm[boff];
                Brl[ks] = *(const short8*)&Wl[boff];
            }
#pragma unroll
            for (int ks = 0; ks < KS; ++ks) {
                int koff = ks * 32 + q * 8;
                int r0 = (lo16 + tap) * STR + koff;
                int r1 = (16 + lo16 + tap) * STR + koff;
                short8 a0h = *(const short8*)&AhL[r0];
                short8 a0m = *(const short8*)&AmL[r0];
                short8 a0l = *(const short8*)&AlL[r0];
                short8 a1h = *(const short8*)&AhL[r1];
                short8 a1m = *(const short8*)&AmL[r1];
                short8 a1l = *(const short8*)&AlL[r1];
                acc0 = __builtin_amdgcn_mfma_f32_16x16x32_bf16(a0h, Brh[ks], acc0, 0, 0, 0);
                acc0 = __builtin_amdgcn_mfma_f32_16x16x32_bf16(a0h, Brm[ks], acc0, 0, 0, 0);
                acc0 = __builtin_amdgcn_mfma_f32_16x16x32_bf16(a0m, Brh[ks], acc0, 0, 0, 0);
                acc0 = __builtin_amdgcn_mfma_f32_16x16x32_bf16(a0h, Brl[ks], acc0, 0, 0, 0);
                acc0 = __builtin_amdgcn_mfma_f32_16x16x32_bf16(a0m, Brm[ks], acc0, 0, 0, 0);
                acc0 = __builtin_amdgcn_mfma_f32_16x16x32_bf16(a0l, Brh[ks], acc0, 0, 0, 0);
                acc1 = __builtin_amdgcn_mfma_f32_16x16x32_bf16(a1h, Brh[ks], acc1, 0, 0, 0);
                acc1 = __builtin_amdgcn_mfma_f32_16x16x32_bf16(a1h, Brm[ks], acc1, 0, 0, 0);
                acc1 = __builtin_amdgcn_mfma_f32_16x16x32_bf16(a1m, Brh[ks], acc1, 0, 0, 0);
                acc1 = __builtin_amdgcn_mfma_f32_16x16x32_bf16(a1h, Brl[ks], acc1, 0, 0, 0);
                acc1 = __builtin_amdgcn_mfma_f32_16x16x32_bf16(a1m, Brm[ks], acc1, 0, 0, 0);
                acc1 = __builtin_amdgcn_mfma_f32_16x16x32_bf16(a1l, Brh[ks], acc1, 0, 0, 0);
            }
        }
#pragma unroll
        for (int mt = 0; mt < 2; ++mt) {
            f32x4 a = mt ? acc1 : acc0;
#pragma unroll
            for (int r = 0; r < 4; ++r) {
                int row = m0 + mt * 16 + q * 4 + r;
                float v = fmaxf(gv * (a[r] + cbv) + bbv, 0.f);
                size_t o = (size_t)row * 256 + ncol;
                split3(v, oh[o], om[o], ol[o]);
            }
        }
    }
}

// ---------------- conv boundary fixup: wave-per-co recompute of rows l=0 and l=2047 ----------------
template <int CI>
__global__ __launch_bounds__(256) void convfix_k(const u16* __restrict__ inh, const u16* __restrict__ inm,
                                                 const u16* __restrict__ inl, const u16* __restrict__ wh,
                                                 const u16* __restrict__ wm, const u16* __restrict__ wl,
                                                 const float* __restrict__ cb, const float* __restrict__ bg,
                                                 const float* __restrict__ bb, u16* __restrict__ oh,
                                                 u16* __restrict__ om, u16* __restrict__ ol) {
    int b = blockIdx.x, side = blockIdx.y;
    int w = threadIdx.x >> 6, lane = threadIdx.x & 63;
    int co = blockIdx.z * 4 + w;
    int l = side ? (LSEQ - 1) : 0;
    int tap0 = side ? 0 : 1;
    float acc = 0.f;
#pragma unroll
    for (int tp = 0; tp < 2; ++tp) {
        int tap = tap0 + tp;
        int li = l + tap - 1;
        size_t ibase = ((size_t)b * LSEQ + li) * CI;
        size_t wbase = ((size_t)(tap * 256) + co) * CI;
        for (int ci = lane; ci < CI; ci += 64)
            acc += rc3(inh, inm, inl, ibase + ci) * rc3(wh, wm, wl, wbase + ci);
    }
    for (int off = 32; off; off >>= 1) acc += __shfl_xor(acc, off, 64);
    if (lane == 0) {
        float v = fmaxf(bg[co] * (acc + cb[co]) + bb[co], 0.f);
        size_t o = ((size_t)b * LSEQ + l) * 256 + co;
        split3(v, oh[o], om[o], ol[o]);
    }
}

// ---------------- LayerNorm, wave-per-row -> split planes ----------------
__global__ __launch_bounds__(256) void ln_k(const float* __restrict__ xin, const float* __restrict__ g,
                                            const float* __restrict__ b, u16* __restrict__ oh,
                                            u16* __restrict__ om, u16* __restrict__ ol) {
    int t = threadIdx.x;
    int w = t >> 6, lane = t & 63;
    size_t row = (size_t)blockIdx.x * 4 + w;
    float4 v = *(const float4*)&xin[row * 256 + lane * 4];
    float s = v.x + v.y + v.z + v.w;
    float qq = v.x * v.x + v.y * v.y + v.z * v.z + v.w * v.w;
    for (int off = 32; off; off >>= 1) {
        s += __shfl_xor(s, off, 64);
        qq += __shfl_xor(qq, off, 64);
    }
    float m = s * (1.f / 256.f);
    float var = qq * (1.f / 256.f) - m * m;
    float r = rsqrtf(var + 1e-5f);
    float4 gg = *(const float4*)&g[lane * 4];
    float4 bb4 = *(const float4*)&b[lane * 4];
    float o0 = (v.x - m) * r * gg.x + bb4.x;
    float o1 = (v.y - m) * r * gg.y + bb4.y;
    float o2 = (v.z - m) * r * gg.z + bb4.z;
    float o3 = (v.w - m) * r * gg.w + bb4.w;
    u16 h[4], mm[4], ll[4];
    split3(o0, h[0], mm[0], ll[0]);
    split3(o1, h[1], mm[1], ll[1]);
    split3(o2, h[2], mm[2], ll[2]);
    split3(o3, h[3], mm[3], ll[3]);
    size_t i = row * 256 + lane * 4;
    uint2 p;
    p.x = (u32)h[0] | ((u32)h[1] << 16); p.y = (u32)h[2] | ((u32)h[3] << 16);
    *(uint2*)&oh[i] = p;
    p.x = (u32)mm[0] | ((u32)mm[1] << 16); p.y = (u32)mm[2] | ((u32)mm[3] << 16);
    *(uint2*)&om[i] = p;
    p.x = (u32)ll[0] | ((u32)ll[1] << 16); p.y = (u32)ll[2] | ((u32)ll[3] << 16);
    *(uint2*)&ol[i] = p;
}

// ---------------- chunked scan pass 1: 4 states/thread, 64 d per block ----------------
__global__ __launch_bounds__(256) void scan1_k(const float* __restrict__ dtbuf, const u16* __restrict__ uh,
                                               const u16* __restrict__ um, const u16* __restrict__ ul,
                                               const float* __restrict__ bc, const float* __restrict__ A_log,
                                               float* __restrict__ stA, float* __restrict__ stB) {
    int c = blockIdx.x, dgq = blockIdx.y;
    int b = blockIdx.z >> 1, dir = blockIdx.z & 1;
    int t = threadIdx.x;
    int dl = t >> 2, ng = t & 3;
    int d = dgq * 64 + dl;
    float4 Alv = *(const float4*)&A_log[(dir * 256 + d) * 16 + ng * 4];
    float Ac0 = -__expf(Alv.x), Ac1 = -__expf(Alv.y), Ac2 = -__expf(Alv.z), Ac3 = -__expf(Alv.w);
    const float* dtp = dtbuf + (size_t)dir * SZ;
    __shared__ __attribute__((aligned(16))) float s_dt[CT * 68];
    __shared__ __attribute__((aligned(16))) float s_u[CT * 68];
    __shared__ __attribute__((aligned(16))) float s_bu[CT * 20];
#pragma unroll
    for (int rep = 0; rep < 2; ++rep) {
        int idx = t + rep * 256;
        int i = idx >> 4, seg = idx & 15;
        int sq = c * CT + i;
        int tt = dir ? (LSEQ - 1 - sq) : sq;
        size_t rowoff = ((size_t)b * LSEQ + tt) * 256 + dgq * 64 + seg * 4;
        *(float4*)&s_dt[i * 68 + seg * 4] = *(const float4*)&dtp[rowoff];
        uint2 hh = *(const uint2*)&uh[rowoff], mm = *(const uint2*)&um[rowoff], ll = *(const uint2*)&ul[rowoff];
        float4 vv;
        vv.x = b2f(hh.x << 16) + b2f(mm.x << 16) + b2f(ll.x << 16);
        vv.y = b2f(hh.x & 0xFFFF0000u) + b2f(mm.x & 0xFFFF0000u) + b2f(ll.x & 0xFFFF0000u);
        vv.z = b2f(hh.y << 16) + b2f(mm.y << 16) + b2f(ll.y << 16);
        vv.w = b2f(hh.y & 0xFFFF0000u) + b2f(mm.y & 0xFFFF0000u) + b2f(ll.y & 0xFFFF0000u);
        *(float4*)&s_u[i * 68 + seg * 4] = vv;
    }
    if (t < 128) {
        int i = t >> 2, seg = t & 3;
        int sq = c * CT + i;
        int tt = dir ? (LSEQ - 1 - sq) : sq;
        *(float4*)&s_bu[i * 20 + seg * 4] = *(const float4*)&bc[((size_t)b * LSEQ + tt) * 64 + dir * 32 + seg * 4];
    }
    __syncthreads();
    float h0 = 0.f, h1 = 0.f, h2 = 0.f, h3 = 0.f;
    float A0 = 1.f, A1 = 1.f, A2 = 1.f, A3 = 1.f;
#pragma unroll
    for (int i = 0; i < CT; ++i) {
        float dtv = s_dt[i * 68 + dl];
        float uv = s_u[i * 68 + dl];
        float4 bu = *(const float4*)&s_bu[i * 20 + ng * 4];
        float du = dtv * uv;
        float a0 = __expf(dtv * Ac0), a1 = __expf(dtv * Ac1), a2 = __expf(dtv * Ac2), a3 = __expf(dtv * Ac3);
        A0 *= a0; A1 *= a1; A2 *= a2; A3 *= a3;
        h0 = a0 * h0 + du * bu.x;
        h1 = a1 * h1 + du * bu.y;
        h2 = a2 * h2 + du * bu.z;
        h3 = a3 * h3 + du * bu.w;
    }
    size_t o = ((size_t)(b * 2 + dir) * NCH + c) * 4096 + dgq * 1024 + dl * 16 + ng * 4;
    float4 av = {A0, A1, A2, A3};
    float4 hv = {h0, h1, h2, h3};
    *(float4*)&stA[o] = av;
    *(float4*)&stB[o] = hv;
}

// ---------------- chunked scan pass 2 (state layout d*16+n, unchanged) ----------------
__global__ __launch_bounds__(256) void scan2_k(const float* __restrict__ stA, const float* __restrict__ stB,
                                               float* __restrict__ stH) {
    int g = blockIdx.x * 256 + threadIdx.x;
    int bd = g >> 12;
    int idx = g & 4095;
    size_t base = (size_t)bd * NCH * 4096 + idx;
    float h = 0.f;
#pragma unroll 8
    for (int c = 0; c < NCH; ++c) {
        stH[base + (size_t)c * 4096] = h;
        h = stA[base + (size_t)c * 4096] * h + stB[base + (size_t)c * 4096];
    }
}

// ---------------- chunked scan pass 3: seeded recompute + 4-wide dot + 2-shuffle reduce ----------------
__global__ __launch_bounds__(256) void scan3_k(const float* __restrict__ dtbuf, const u16* __restrict__ uh,
                                               const u16* __restrict__ um, const u16* __restrict__ ul,
                                               const float* __restrict__ bc, const float* __restrict__ A_log,
                                               const float* __restrict__ Dp, const float* __restrict__ stH,
                                               float* __restrict__ y0, float* __restrict__ y1) {
    int c = blockIdx.x, dgq = blockIdx.y;
    int b = blockIdx.z >> 1, dir = blockIdx.z & 1;
    int t = threadIdx.x;
    int dl = t >> 2, ng = t & 3;
    int d = dgq * 64 + dl;
    float4 Alv = *(const float4*)&A_log[(dir * 256 + d) * 16 + ng * 4];
    float Ac0 = -__expf(Alv.x), Ac1 = -__expf(Alv.y), Ac2 = -__expf(Alv.z), Ac3 = -__expf(Alv.w);
    float Dv = Dp[dir * 256 + d];
    const float* dtp = dtbuf + (size_t)dir * SZ;
    float* yout = dir ? y1 : y0;
    __shared__ __attribute__((aligned(16))) float s_dt[CT * 68];
    __shared__ __attribute__((aligned(16))) float s_u[CT * 68];
    __shared__ __attribute__((aligned(16))) float s_bc[CT * 36];
#pragma unroll
    for (int rep = 0; rep < 2; ++rep) {
        int idx = t + rep * 256;
        int i = idx >> 4, seg = idx & 15;
        int sq = c * CT + i;
        int tt = dir ? (LSEQ - 1 - sq) : sq;
        size_t rowoff = ((size_t)b * LSEQ + tt) * 256 + dgq * 64 + seg * 4;
        *(float4*)&s_dt[i * 68 + seg * 4] = *(const float4*)&dtp[rowoff];
        uint2 hh = *(const uint2*)&uh[rowoff], mm = *(const uint2*)&um[rowoff], ll = *(const uint2*)&ul[rowoff];
        float4 vv;
        vv.x = b2f(hh.x << 16) + b2f(mm.x << 16) + b2f(ll.x << 16);
        vv.y = b2f(hh.x & 0xFFFF0000u) + b2f(mm.x & 0xFFFF0000u) + b2f(ll.x & 0xFFFF0000u);
        vv.z = b2f(hh.y << 16) + b2f(mm.y << 16) + b2f(ll.y << 16);
        vv.w = b2f(hh.y & 0xFFFF0000u) + b2f(mm.y & 0xFFFF0000u) + b2f(ll.y & 0xFFFF0000u);
        *(float4*)&s_u[i * 68 + seg * 4] = vv;
    }
    {
        int i = t >> 3, seg = t & 7;
        int sq = c * CT + i;
        int tt = dir ? (LSEQ - 1 - sq) : sq;
        *(float4*)&s_bc[i * 36 + seg * 4] = *(const float4*)&bc[((size_t)b * LSEQ + tt) * 64 + dir * 32 + seg * 4];
    }
    __syncthreads();
    size_t o = ((size_t)(b * 2 + dir) * NCH + c) * 4096 + dgq * 1024 + dl * 16 + ng * 4;
    float4 hv = *(const float4*)&stH[o];
    float h0 = hv.x, h1 = hv.y, h2 = hv.z, h3 = hv.w;
    int base_sq = c * CT;
#pragma unroll
    for (int i = 0; i < CT; ++i) {
        float dtv = s_dt[i * 68 + dl];
        float uv = s_u[i * 68 + dl];
        float4 bu = *(const float4*)&s_bc[i * 36 + ng * 4];
        float4 cv = *(const float4*)&s_bc[i * 36 + 16 + ng * 4];
        float du = dtv * uv;
        float a0 = __expf(dtv * Ac0), a1 = __expf(dtv * Ac1), a2 = __expf(dtv * Ac2), a3 = __expf(dtv * Ac3);
        h0 = a0 * h0 + du * bu.x;
        h1 = a1 * h1 + du * bu.y;
        h2 = a2 * h2 + du * bu.z;
        h3 = a3 * h3 + du * bu.w;
        float p = h0 * cv.x + h1 * cv.y + h2 * cv.z + h3 * cv.w;
        p += __shfl_xor(p, 1, 64);
        p += __shfl_xor(p, 2, 64);
        if (ng == 0) {
            int sq = base_sq + i;
            int tt = dir ? (LSEQ - 1 - sq) : sq;
            yout[((size_t)b * LSEQ + tt) * 256 + d] = p + uv * Dv;
        }
    }
}

// ---------------- gate -> split planes ----------------
__global__ __launch_bounds__(256) void gate_k(const float* __restrict__ y0, const float* __restrict__ y1,
                                              const float* __restrict__ z, u16* __restrict__ gh,
                                              u16* __restrict__ gm, u16* __restrict__ gl) {
    size_t i = (size_t)blockIdx.x * 256 + threadIdx.x;
    float4 v0 = ((const float4*)y0)[i];
    float4 v1 = ((const float4*)y1)[i];
    float4 vz = ((const float4*)z)[i];
    float g0 = (v0.x + v1.x) * (vz.x / (1.f + __expf(-vz.x)));
    float g1 = (v0.y + v1.y) * (vz.y / (1.f + __expf(-vz.y)));
    float g2 = (v0.z + v1.z) * (vz.z / (1.f + __expf(-vz.z)));
    float g3 = (v0.w + v1.w) * (vz.w / (1.f + __expf(-vz.w)));
    u16 h[4], m[4], l[4];
    split3(g0, h[0], m[0], l[0]);
    split3(g1, h[1], m[1], l[1]);
    split3(g2, h[2], m[2], l[2]);
    split3(g3, h[3], m[3], l[3]);
    uint2 p;
    p.x = (u32)h[0] | ((u32)h[1] << 16); p.y = (u32)h[2] | ((u32)h[3] << 16);
    *(uint2*)&gh[i * 4] = p;
    p.x = (u32)m[0] | ((u32)m[1] << 16); p.y = (u32)m[2] | ((u32)m[3] << 16);
    *(uint2*)&gm[i * 4] = p;
    p.x = (u32)l[0] | ((u32)l[1] << 16); p.y = (u32)l[2] | ((u32)l[3] << 16);
    *(uint2*)&gl[i * 4] = p;
}

// ---------------- means over L (two-stage); x_cnn from split planes ----------------
__global__ __launch_bounds__(256) void mean1_k(const u16* __restrict__ ch, const u16* __restrict__ cm,
                                               const u16* __restrict__ cl, const float* __restrict__ xm,
                                               float* __restrict__ part) {
    int b = blockIdx.x, chk = blockIdx.y, t = threadIdx.x;
    float s1 = 0.f, s2 = 0.f;
    for (int l = chk * 64; l < chk * 64 + 64; ++l) {
        size_t o = ((size_t)b * LSEQ + l) * 256 + t;
        s1 += rc3(ch, cm, cl, o);
        s2 += xm[o];
    }
    part[(b * 32 + chk) * 512 + t] = s1;
    part[(b * 32 + chk) * 512 + 256 + t] = s2;
}

__global__ __launch_bounds__(256) void mean2_k(const float* __restrict__ part, float* __restrict__ xflat) {
    int b = blockIdx.x, t = threadIdx.x;
    float s1 = 0.f, s2 = 0.f;
    for (int ch = 0; ch < 32; ++ch) {
        s1 += part[(b * 32 + ch) * 512 + t];
        s2 += part[(b * 32 + ch) * 512 + 256 + t];
    }
    xflat[b * 528 + t] = s1 * (1.f / 2048.f);
    xflat[b * 528 + 256 + t] = s2 * (1.f / 2048.f);
}

// ---------------- x_main two-stage ----------------
__global__ __launch_bounds__(256) void xmain1_k(const float* __restrict__ x, const float* __restrict__ w1,
                                                float* __restrict__ part2) {
    int b = blockIdx.x, ch = blockIdx.y, t = threadIdx.x;
    float acc = 0.f;
    for (int k = ch * 128; k < ch * 128 + 128; ++k) acc += x[b * LSEQ + k] * w1[k * 256 + t];
    part2[(b * 16 + ch) * 256 + t] = acc;
}

__global__ __launch_bounds__(256) void xmain2_k(const float* __restrict__ part2, const float* __restrict__ b1,
                                                const float* __restrict__ w2, const float* __restrict__ b2,
                                                float* __restrict__ xflat) {
    int b = blockIdx.x, t = threadIdx.x;
    float acc = b1[t];
    for (int ch = 0; ch < 16; ++ch) acc += part2[(b * 16 + ch) * 256 + t];
    __shared__ float h[256];
    h[t] = fmaxf(acc, 0.f);
    __syncthreads();
    if (t < 16) {
        float a2 = b2[t];
        for (int k = 0; k < 256; ++k) a2 += h[k] * w2[k * 16 + t];
        xflat[b * 528 + 512 + t] = a2;
    }
}

// ---------------- main_weights ----------------
__global__ void mew_k(const float* __restrict__ mew, float* __restrict__ outp) {
    int i = blockIdx.x * 256 + threadIdx.x;
    if (i < LSEQ) outp[4 + i] = 1.f / (1.f + __expf(-mew[i]));
}

// ---------------- pair scores ----------------
__global__ __launch_bounds__(256) void scores_k(const float* __restrict__ xm, const int* __restrict__ pairs,
                                                const float* __restrict__ epw, const float* __restrict__ epb,
                                                float* __restrict__ scores) {
    int p = blockIdx.x;
    int t = threadIdx.x;
    int w = t >> 6, lane = t & 63;
    int pi = pairs[2 * p], pj = pairs[2 * p + 1];
    float acc = 0.f;
    for (int c = lane; c < 256; c += 64) {
        acc += xm[((size_t)w * LSEQ + pi) * 256 + c] * epw[c];
        acc += xm[((size_t)w * LSEQ + pj) * 256 + c] * epw[256 + c];
    }
    for (int off = 32; off; off >>= 1) acc += __shfl_xor(acc, off, 64);
    __shared__ float sb[4];
    if (lane == 0) sb[w] = 1.f / (1.f + __expf(-(acc + epb[0])));
    __syncthreads();
    if (t == 0) scores[p] = 0.25f * (sb[0] + sb[1] + sb[2] + sb[3]);
}

// ---------------- top-k (full stable rank of 200) ----------------
__global__ __launch_bounds__(256) void topk_k(const float* __restrict__ scores, const int* __restrict__ pairs,
                                              float* __restrict__ outp) {
    __shared__ float s[200];
    int t = threadIdx.x;
    if (t < 200) s[t] = scores[t];
    __syncthreads();
    if (t < 200) {
        float v = s[t];
        int r = 0;
        for (int q = 0; q < 200; ++q) {
            float u = s[q];
            r += (u > v) || (u == v && q < t);
        }
        outp[2052 + 2 * r] = (float)pairs[2 * t];
        outp[2052 + 2 * r + 1] = (float)pairs[2 * t + 1];
        outp[2452 + r] = v;
    }
}

// ---------------- epi MLP + out head ----------------
__global__ __launch_bounds__(128) void epi_k(const float* __restrict__ xflat, const float* __restrict__ w1,
                                             const float* __restrict__ b1, const float* __restrict__ w2,
                                             const float* __restrict__ b2, const float* __restrict__ w3,
                                             const float* __restrict__ b3, const float* __restrict__ ow1,
                                             const float* __restrict__ ob1, const float* __restrict__ ow2,
                                             const float* __restrict__ ob2, float* __restrict__ outp) {
    int b = blockIdx.x, t = threadIdx.x;
    __shared__ float xb[528], e1[128], e2[64], e3[32], o1[16];
    for (int idx = t; idx < 528; idx += 128) xb[idx] = xflat[b * 528 + idx];
    __syncthreads();
    {
        float a = b1[t];
        for (int k = 0; k < 528; ++k) a += xb[k] * w1[k * 128 + t];
        e1[t] = fmaxf(a, 0.f);
    }
    __syncthreads();
    if (t < 64) {
        float a = b2[t];
        for (int k = 0; k < 128; ++k) a += e1[k] * w2[k * 64 + t];
        e2[t] = fmaxf(a, 0.f);
    }
    __syncthreads();
    if (t < 32) {
        float a = b3[t];
        for (int k = 0; k < 64; ++k) a += e2[k] * w3[k * 32 + t];
        e3[t] = a;
    }
    __syncthreads();
    if (t < 16) {
        float a = ob1[t];
        for (int k = 0; k < 32; ++k) a += e3[k] * ow1[k * 16 + t];
        o1[t] = fmaxf(a, 0.f);
    }
    __syncthreads();
    if (t == 0) {
        float a = ob2[0];
        for (int k = 0; k < 16; ++k) a += o1[k] * ow2[k];
        outp[b] = 1.f / (1.f + __expf(-a));
    }
}

extern "C" void kernel_launch(void* const* d_in, const int* in_sizes, int n_in, void* d_out, int out_size,
                              void* d_ws, size_t ws_size, hipStream_t stream) {
    (void)in_sizes; (void)n_in; (void)out_size; (void)ws_size;
    const float* x = (const float*)d_in[0];
    const int* pairs = (const int*)d_in[1];
    const float* emb_w = (const float*)d_in[2];
    const float* emb_b = (const float*)d_in[3];
    const float* conv0_w = (const float*)d_in[4];
    const float* conv0_b = (const float*)d_in[5];
    const float* bn0_g = (const float*)d_in[6];
    const float* bn0_b = (const float*)d_in[7];
    const float* conv1_w = (const float*)d_in[8];
    const float* conv1_b = (const float*)d_in[9];
    const float* bn1_g = (const float*)d_in[10];
    const float* bn1_b = (const float*)d_in[11];
    const float* conv2_w = (const float*)d_in[12];
    const float* conv2_b = (const float*)d_in[13];
    const float* bn2_g = (const float*)d_in[14];
    const float* bn2_b = (const float*)d_in[15];
    const float* conv3_w = (const float*)d_in[16];
    const float* conv3_b = (const float*)d_in[17];
    const float* bn3_g = (const float*)d_in[18];
    const float* bn3_b = (const float*)d_in[19];
    const float* fp_w = (const float*)d_in[20];
    const float* fp_b = (const float*)d_in[21];
    const float* mb_norm_g = (const float*)d_in[22];
    const float* mb_norm_b = (const float*)d_in[23];
    const float* mb_in_w = (const float*)d_in[24];
    const float* mb_in_b = (const float*)d_in[25];
    const float* mb_A_log = (const float*)d_in[26];
    const float* mb_dt_w = (const float*)d_in[27];
    const float* mb_dt_b = (const float*)d_in[28];
    const float* mb_B_w = (const float*)d_in[29];
    const float* mb_C_w = (const float*)d_in[30];
    const float* mb_D = (const float*)d_in[31];
    const float* mb_out_w = (const float*)d_in[32];
    const float* mb_out_b = (const float*)d_in[33];
    const float* me_w1 = (const float*)d_in[34];
    const float* me_b1 = (const float*)d_in[35];
    const float* me_w2 = (const float*)d_in[36];
    const float* me_b2 = (const float*)d_in[37];
    const float* mew = (const float*)d_in[38];
    const float* ep_w = (const float*)d_in[39];
    const float* ep_b = (const float*)d_in[40];
    const float* epi_w1 = (const float*)d_in[41];
    const float* epi_b1 = (const float*)d_in[42];
    const float* epi_w2 = (const float*)d_in[43];
    const float* epi_b2 = (const float*)d_in[44];
    const float* epi_w3 = (const float*)d_in[45];
    const float* epi_b3 = (const float*)d_in[46];
    const float* out_w1 = (const float*)d_in[47];
    const float* out_b1 = (const float*)d_in[48];
    const float* out_w2 = (const float*)d_in[49];
    const float* out_b2 = (const float*)d_in[50];
    float* outp = (float*)d_out;

    float* ws = (float*)d_ws;
    size_t off = 0;
    auto AL = [&](size_t n) { float* p = ws + off; off += n; return p; };
    float* xm = AL(SZ);
    float* z = AL(SZ);
    float* dtb = AL(2 * SZ); // c0 split planes aliased inside (dead before dt written)
    float* y0 = AL(SZ);      // stA alias
    float* y1 = AL(SZ);      // stB alias
    float* bcb = AL(SZ / 4);
    AL(128);
    float* c1s = AL(SZ + SZ / 2); // 3 planes x SZ u16 ; also ln/gate splits + stH alias
    AL(128);
    float* c2s = AL(SZ + SZ / 2); // also u split planes
    AL(128);
    float* c3s = AL(SZ + SZ / 2);
    AL(128);
    float* wfp = AL(98304);
    float* win = AL(393216);
    float* wdt = AL(393216);
    float* wou = AL(196608);
    float* wc1 = AL(147456);
    float* wc2 = AL(294912);
    float* wc3 = AL(294912);
    float* wbc = AL(49152);
    float* part = AL(65536);
    float* part2 = AL(16384);
    float* xflat = AL(2112);
    float* scoresb = AL(256);

    u16* c0h = (u16*)dtb + 128;
    u16* c0m = c0h + SZ / 2;
    u16* c0l = c0m + SZ / 2;
    u16* c1h = (u16*)c1s; u16* c1m = c1h + SZ; u16* c1l = c1m + SZ;
    u16* c2h = (u16*)c2s; u16* c2m = c2h + SZ; u16* c2l = c2m + SZ;
    u16* c3h = (u16*)c3s; u16* c3m = c3h + SZ; u16* c3l = c3m + SZ;
    float* stH = c1s;
    u16* wfph = (u16*)wfp; u16* wfpm = wfph + 65536; u16* wfpl = wfpm + 65536;
    u16* winh = (u16*)win; u16* winm = winh + 262144; u16* winl = winm + 262144;
    u16* wdth = (u16*)wdt; u16* wdtm = wdth + 262144; u16* wdtl = wdtm + 262144;
    u16* wouh = (u16*)wou; u16* woum = wouh + 131072; u16* woul = woum + 131072;
    u16* wc1h = (u16*)wc1; u16* wc1m = wc1h + 98304; u16* wc1l = wc1m + 98304;
    u16* wc2h = (u16*)wc2; u16* wc2m = wc2h + 196608; u16* wc2l = wc2m + 196608;
    u16* wc3h = (u16*)wc3; u16* wc3m = wc3h + 196608; u16* wc3l = wc3m + 196608;
    u16* wbch = (u16*)wbc; u16* wbcm = wbch + 32768; u16* wbcl = wbcm + 32768;

    // weight prep
    wsplit_t<<<256, 256, 0, stream>>>(fp_w, 256, 256, 65536, wfph, wfpm, wfpl);
    wsplit_t<<<1024, 256, 0, stream>>>(mb_in_w, 256, 512, 262144, winh, winm, winl);
    wsplit_t<<<1024, 256, 0, stream>>>(mb_dt_w, 256, 256, 262144, wdth, wdtm, wdtl);
    wsplit_t<<<512, 256, 0, stream>>>(mb_out_w, 256, 256, 131072, wouh, woum, woul);
    wsplit_conv<<<384, 256, 0, stream>>>(conv1_w, 128, 98304, wc1h, wc1m, wc1l);
    wsplit_conv<<<768, 256, 0, stream>>>(conv2_w, 256, 196608, wc2h, wc2m, wc2l);
    wsplit_conv<<<768, 256, 0, stream>>>(conv3_w, 256, 196608, wc3h, wc3m, wc3l);
    wsplit_bc<<<128, 256, 0, stream>>>(mb_B_w, mb_C_w, wbch, wbcm, wbcl);

    // CNN
    conv0_k<<<4096, 256, 0, stream>>>(x, conv0_w, conv0_b, bn0_g, bn0_b, c0h, c0m, c0l);
    conv_mfma_k<128, 4, 512><<<dim3(128, 2), 512, 0, stream>>>(c0h, c0m, c0l, wc1h, wc1m, wc1l, conv1_b, bn1_g,
                                                               bn1_b, c1h, c1m, c1l);
    convfix_k<128><<<dim3(4, 2, 64), 256, 0, stream>>>(c0h, c0m, c0l, wc1h, wc1m, wc1l, conv1_b, bn1_g, bn1_b,
                                                       c1h, c1m, c1l);
    conv_mfma_k<256, 8, 512><<<dim3(128, 2), 512, 0, stream>>>(c1h, c1m, c1l, wc2h, wc2m, wc2l, conv2_b, bn2_g,
                                                               bn2_b, c2h, c2m, c2l);
    convfix_k<256><<<dim3(4, 2, 64), 256, 0, stream>>>(c1h, c1m, c1l, wc2h, wc2m, wc2l, conv2_b, bn2_g, bn2_b,
                                                       c2h, c2m, c2l);
    conv_mfma_k<256, 8, 512><<<dim3(128, 2), 512, 0, stream>>>(c2h, c2m, c2l, wc3h, wc3m, wc3l, conv3_b, bn3_g,
                                                               bn3_b, c3h, c3m, c3l);
    convfix_k<256><<<dim3(4, 2, 64), 256, 0, stream>>>(c2h, c2m, c2l, wc3h, wc3m, wc3l, conv3_b, bn3_g, bn3_b,
                                                       c3h, c3m, c3l);

    // xm = x_embed + x_cnn@fp_w + fp_b + PE
    mfma_gemm_k<512><<<dim3(128, 2), 512, 0, stream>>>(c3h, c3m, c3l, wfph, wfpm, wfpl, fp_b, MODE_FP, xm,
                                                       nullptr, nullptr, nullptr, nullptr, x, emb_w, emb_b,
                                                       0, 0, 0);

    for (int l = 0; l < 2; ++l) {
        ln_k<<<2048, 256, 0, stream>>>(xm, mb_norm_g + l * 256, mb_norm_b + l * 256, c1h, c1m, c1l);
        mfma_gemm_k<512><<<dim3(128, 4), 512, 0, stream>>>(c1h, c1m, c1l, winh + l * 131072, winm + l * 131072,
                                                           winl + l * 131072, mb_in_b + l * 512, MODE_UZ, z,
                                                           c2h, c2m, c2l, nullptr, nullptr, nullptr, nullptr,
                                                           0, 0, 0);
        mfma_gemm_k<512><<<dim3(128, 2, 2), 512, 0, stream>>>(c2h, c2m, c2l, wdth + 2 * l * 65536,
                                                              wdtm + 2 * l * 65536, wdtl + 2 * l * 65536,
                                                              mb_dt_b + l * 512, MODE_DT, dtb,
                                                              nullptr, nullptr, nullptr, nullptr, nullptr, nullptr,
                                                              nullptr, 65536, 256, (long)SZ);
        mfma_gemm_k<256><<<dim3(128, 1), 256, 0, stream>>>(c2h, c2m, c2l, wbch + l * 16384, wbcm + l * 16384,
                                                           wbcl + l * 16384, nullptr, MODE_BC, bcb,
                                                           nullptr, nullptr, nullptr, nullptr, nullptr, nullptr,
                                                           nullptr, 0, 0, 0);
        scan1_k<<<dim3(NCH, 4, 8), 256, 0, stream>>>(dtb, c2h, c2m, c2l, bcb, mb_A_log + l * 8192, y0, y1);
        scan2_k<<<128, 256, 0, stream>>>(y0, y1, stH);
        scan3_k<<<dim3(NCH, 4, 8), 256, 0, stream>>>(dtb, c2h, c2m, c2l, bcb, mb_A_log + l * 8192, mb_D + l * 512,
                                                     stH, y0, y1);
        gate_k<<<2048, 256, 0, stream>>>(y0, y1, z, c1h, c1m, c1l);
        mfma_gemm_k<512><<<dim3(128, 2), 512, 0, stream>>>(c1h, c1m, c1l, wouh + l * 65536, woum + l * 65536,
                                                           woul + l * 65536, mb_out_b + l * 256, MODE_OUT, xm,
                                                           nullptr, nullptr, nullptr, xm, nullptr, nullptr,
                                                           nullptr, 0, 0, 0);
    }

    // heads
    mean1_k<<<dim3(4, 32), 256, 0, stream>>>(c3h, c3m, c3l, xm, part);
    mean2_k<<<4, 256, 0, stream>>>(part, xflat);
    xmain1_k<<<dim3(4, 16), 256, 0, stream>>>(x, me_w1, part2);
    xmain2_k<<<4, 256, 0, stream>>>(part2, me_b1, me_w2, me_b2, xflat);
    mew_k<<<8, 256, 0, stream>>>(mew, outp);
    scores_k<<<200, 256, 0, stream>>>(xm, pairs, ep_w, ep_b, scoresb);
    topk_k<<<1, 256, 0, stream>>>(scoresb, pairs, outp);
    epi_k<<<4, 128, 0, stream>>>(xflat, epi_w1, epi_b1, epi_w2, epi_b2, epi_w3, epi_b3, out_w1, out_b1, out_w2,
                                 out_b2, outp);
}

// Round 11
// 703.219 us; speedup vs baseline: 1.3418x; 1.1374x over previous
//
#include <hip/hip_runtime.h>
#include <math.h>

typedef unsigned short u16;
typedef unsigned int u32;
typedef __attribute__((ext_vector_type(8))) short short8;
typedef __attribute__((ext_vector_type(4))) float f32x4;

#define BB 4
#define LSEQ 2048
static const size_t SZ = (size_t)BB * LSEQ * 256; // 2097152

#define NCH 64
#define CT 32

__device__ __forceinline__ float b2f(u32 u) { return __uint_as_float(u); }

// 3-way bf16 split: x = h + m + l - eps, |eps| <= 2^-27 |x|
__device__ __forceinline__ void split3(float x, u16& h, u16& m, u16& l) {
    u32 xu = __float_as_uint(x);
    u32 hu = (xu + 0x7FFFu + ((xu >> 16) & 1u)) & 0xFFFF0000u;
    h = (u16)(hu >> 16);
    float r1 = x - b2f(hu);
    u32 r1u = __float_as_uint(r1);
    u32 mu = (r1u + 0x7FFFu + ((r1u >> 16) & 1u)) & 0xFFFF0000u;
    m = (u16)(mu >> 16);
    float r2 = r1 - b2f(mu);
    u32 lu = __float_as_uint(r2);
    l = (u16)((lu + 0x7FFFu + ((lu >> 16) & 1u)) >> 16);
}

__device__ __forceinline__ float rc3(const u16* __restrict__ h, const u16* __restrict__ m,
                                     const u16* __restrict__ l, size_t i) {
    return b2f((u32)h[i] << 16) + b2f((u32)m[i] << 16) + b2f((u32)l[i] << 16);
}

// ---------------- weight transpose+split: W[mat][K][N] -> planes [mat][n][k] ----------------
__global__ void wsplit_t(const float* __restrict__ W, int Kd, int Nd, int total,
                         u16* __restrict__ oh, u16* __restrict__ om, u16* __restrict__ ol) {
    int idx = blockIdx.x * 256 + threadIdx.x;
    if (idx >= total) return;
    int per = Kd * Nd;
    int mat = idx / per;
    int r = idx - mat * per;
    int n = r / Kd;
    int k = r - n * Kd;
    float v = W[(size_t)mat * per + (size_t)k * Nd + n];
    split3(v, oh[idx], om[idx], ol[idx]);
}

// ---------------- conv weight split: w[co][ci][3] -> planes [tap][co][ci] ----------------
__global__ void wsplit_conv(const float* __restrict__ w, int CI, int total,
                            u16* __restrict__ oh, u16* __restrict__ om, u16* __restrict__ ol) {
    int idx = blockIdx.x * 256 + threadIdx.x;
    if (idx >= total) return;
    int ci = idx % CI;
    int tmp = idx / CI;
    int co = tmp & 255;
    int tap = tmp >> 8;
    float v = w[(co * CI + ci) * 3 + tap];
    split3(v, oh[idx], om[idx], ol[idx]);
}

// ---------------- B/C weight split for bcproj GEMM: [layer][n(64)][k(256)] ----------------
__global__ void wsplit_bc(const float* __restrict__ Bw, const float* __restrict__ Cw,
                          u16* __restrict__ oh, u16* __restrict__ om, u16* __restrict__ ol) {
    int idx = blockIdx.x * 256 + threadIdx.x; // 32768 total
    int layer = idx >> 14;
    int r = idx & 16383;
    int n = r >> 8, k = r & 255;
    int dir = n >> 5, which = (n >> 4) & 1, col = n & 15;
    const float* src = which ? Cw : Bw;
    float v = src[layer * 8192 + dir * 4096 + k * 16 + col];
    split3(v, oh[idx], om[idx], ol[idx]);
}

// ---------------- conv0: Ci=1, Co=128 -> split planes (B,L,128) ----------------
__global__ __launch_bounds__(256) void conv0_k(const float* __restrict__ x, const float* __restrict__ w,
                                               const float* __restrict__ cb, const float* __restrict__ g,
                                               const float* __restrict__ bb, u16* __restrict__ oh,
                                               u16* __restrict__ om, u16* __restrict__ ol) {
    int gid = blockIdx.x * 256 + threadIdx.x;
    int co = gid & 127;
    int l = (gid >> 7) & (LSEQ - 1);
    int b = gid >> 18;
    const float* xr = x + (size_t)b * LSEQ;
    float xm1 = (l > 0) ? xr[l - 1] : 0.f;
    float x0 = xr[l];
    float xp1 = (l < LSEQ - 1) ? xr[l + 1] : 0.f;
    float v = xm1 * w[co * 3] + x0 * w[co * 3 + 1] + xp1 * w[co * 3 + 2] + cb[co];
    v = fmaxf(g[co] * v + bb[co], 0.f);
    size_t o = ((size_t)b * LSEQ + l) * 128 + co;
    split3(v, oh[o], om[o], ol[o]);
}

#define MODE_FP 0
#define MODE_UZ 1
#define MODE_DT 2
#define MODE_OUT 3
#define MODE_BC 4

// ---------------- MFMA GEMM (NT threads = NT/64 waves, NT/4 cols per block) ----------
// block: 64 rows (2 chunks of 32) x NT/4 cols; B in regs once per wave; A staged per chunk.
template <int NT>
__global__ __launch_bounds__(NT, 2) void mfma_gemm_k(
    const u16* __restrict__ Ah, const u16* __restrict__ Am, const u16* __restrict__ Al,
    const u16* __restrict__ Bh_, const u16* __restrict__ Bm_, const u16* __restrict__ Bl_,
    const float* __restrict__ bias, int mode, float* __restrict__ outf,
    u16* __restrict__ oh, u16* __restrict__ om, u16* __restrict__ ol,
    const float* __restrict__ resid, const float* __restrict__ xv,
    const float* __restrict__ embw, const float* __restrict__ embb,
    int bz, int biasz, long oz) {
    __shared__ __attribute__((aligned(16))) u16 AhL[32 * 264];
    __shared__ __attribute__((aligned(16))) u16 AmL[32 * 264];
    __shared__ __attribute__((aligned(16))) u16 AlL[32 * 264];
    int t = threadIdx.x;
    int w = t >> 6, l = t & 63;
    int lo16 = l & 15, q = l >> 4;
    int zi = blockIdx.z;
    const u16* bh = Bh_ + (size_t)zi * bz;
    const u16* bm = Bm_ + (size_t)zi * bz;
    const u16* bl = Bl_ + (size_t)zi * bz;
    int ncol = blockIdx.y * (NT / 4) + w * 16 + lo16;
    short8 Brh[8], Brm[8], Brl[8];
#pragma unroll
    for (int ks = 0; ks < 8; ++ks) {
        size_t boff = (size_t)ncol * 256 + ks * 32 + q * 8;
        Brh[ks] = *(const short8*)&bh[boff];
        Brm[ks] = *(const short8*)&bm[boff];
        Brl[ks] = *(const short8*)&bl[boff];
    }
    float bv = bias ? bias[biasz * zi + ncol] : 0.f;
    int m_base = blockIdx.x * 64;
    for (int c = 0; c < 2; ++c) {
        int m0 = m_base + c * 32;
        if (c) __syncthreads();
#pragma unroll
        for (int idx = t; idx < 1024; idx += NT) {
            int r = idx >> 5, p = idx & 31;
            size_t goff = (size_t)(m0 + r) * 256 + p * 8;
            int loff = r * 264 + p * 8;
            *(short8*)&AhL[loff] = *(const short8*)&Ah[goff];
            *(short8*)&AmL[loff] = *(const short8*)&Am[goff];
            *(short8*)&AlL[loff] = *(const short8*)&Al[goff];
        }
        __syncthreads();
        f32x4 acc0 = {0.f, 0.f, 0.f, 0.f}, acc1 = {0.f, 0.f, 0.f, 0.f};
#pragma unroll
        for (int ks = 0; ks < 8; ++ks) {
            int koff = ks * 32 + q * 8;
            short8 a0h = *(const short8*)&AhL[lo16 * 264 + koff];
            short8 a0m = *(const short8*)&AmL[lo16 * 264 + koff];
            short8 a0l = *(const short8*)&AlL[lo16 * 264 + koff];
            short8 a1h = *(const short8*)&AhL[(16 + lo16) * 264 + koff];
            short8 a1m = *(const short8*)&AmL[(16 + lo16) * 264 + koff];
            short8 a1l = *(const short8*)&AlL[(16 + lo16) * 264 + koff];
            acc0 = __builtin_amdgcn_mfma_f32_16x16x32_bf16(a0h, Brh[ks], acc0, 0, 0, 0);
            acc0 = __builtin_amdgcn_mfma_f32_16x16x32_bf16(a0h, Brm[ks], acc0, 0, 0, 0);
            acc0 = __builtin_amdgcn_mfma_f32_16x16x32_bf16(a0m, Brh[ks], acc0, 0, 0, 0);
            acc0 = __builtin_amdgcn_mfma_f32_16x16x32_bf16(a0h, Brl[ks], acc0, 0, 0, 0);
            acc0 = __builtin_amdgcn_mfma_f32_16x16x32_bf16(a0m, Brm[ks], acc0, 0, 0, 0);
            acc0 = __builtin_amdgcn_mfma_f32_16x16x32_bf16(a0l, Brh[ks], acc0, 0, 0, 0);
            acc1 = __builtin_amdgcn_mfma_f32_16x16x32_bf16(a1h, Brh[ks], acc1, 0, 0, 0);
            acc1 = __builtin_amdgcn_mfma_f32_16x16x32_bf16(a1h, Brm[ks], acc1, 0, 0, 0);
            acc1 = __builtin_amdgcn_mfma_f32_16x16x32_bf16(a1m, Brh[ks], acc1, 0, 0, 0);
            acc1 = __builtin_amdgcn_mfma_f32_16x16x32_bf16(a1h, Brl[ks], acc1, 0, 0, 0);
            acc1 = __builtin_amdgcn_mfma_f32_16x16x32_bf16(a1m, Brm[ks], acc1, 0, 0, 0);
            acc1 = __builtin_amdgcn_mfma_f32_16x16x32_bf16(a1l, Brh[ks], acc1, 0, 0, 0);
        }
        float freq = 0.f;
        if (mode == MODE_FP) freq = expf(-(float)(ncol & ~1) * (logf(10000.f) / 256.f));
#pragma unroll
        for (int mt = 0; mt < 2; ++mt) {
            f32x4 a = mt ? acc1 : acc0;
#pragma unroll
            for (int r = 0; r < 4; ++r) {
                int row = m0 + mt * 16 + q * 4 + r;
                float v = a[r] + bv;
                size_t o = (size_t)row * 256 + ncol;
                if (mode == MODE_FP) {
                    int li = row & (LSEQ - 1);
                    float ang = (float)li * freq;
                    float pe = (ncol & 1) ? cosf(ang) : sinf(ang);
                    v += xv[row] * embw[ncol] + embb[ncol] + pe;
                    outf[o] = v;
                } else if (mode == MODE_UZ) {
                    if (ncol < 256) {
                        v = v / (1.f + __expf(-v));
                        split3(v, oh[o], om[o], ol[o]);
                    } else {
                        outf[(size_t)row * 256 + ncol - 256] = v;
                    }
                } else if (mode == MODE_DT) {
                    v = (v > 20.f) ? v : log1pf(__expf(v));
                    outf[(size_t)zi * oz + o] = v;
                } else if (mode == MODE_BC) {
                    outf[(size_t)row * 64 + ncol] = v;
                } else {
                    v += resid[o];
                    outf[o] = v;
                }
            }
        }
    }
}

// ---------------- MFMA conv (NT threads): implicit GEMM over 3 taps ----------------
template <int CI, int KS, int NT>
__global__ __launch_bounds__(NT, 2) void conv_mfma_k(
    const u16* __restrict__ Ah, const u16* __restrict__ Am, const u16* __restrict__ Al,
    const u16* __restrict__ Wh, const u16* __restrict__ Wm, const u16* __restrict__ Wl,
    const float* __restrict__ cb, const float* __restrict__ bg, const float* __restrict__ bb,
    u16* __restrict__ oh, u16* __restrict__ om, u16* __restrict__ ol) {
    const int STR = CI + 8;
    __shared__ __attribute__((aligned(16))) u16 AhL[34 * STR];
    __shared__ __attribute__((aligned(16))) u16 AmL[34 * STR];
    __shared__ __attribute__((aligned(16))) u16 AlL[34 * STR];
    int t = threadIdx.x, w = t >> 6, l = t & 63;
    int lo16 = l & 15, q = l >> 4;
    int ncol = blockIdx.y * (NT / 4) + w * 16 + lo16;
    int m_base = blockIdx.x * 64;
    float cbv = cb[ncol], gv = bg[ncol], bbv = bb[ncol];
    for (int c = 0; c < 2; ++c) {
        int m0 = m_base + c * 32;
        if (c) __syncthreads();
        const int PARTS = CI / 8;
        for (int idx = t; idx < 34 * PARTS; idx += NT) {
            int r = idx / PARTS, p = idx - r * PARTS;
            long goff = (long)(m0 - 1 + r) * CI + p * 8;
            int loff = r * STR + p * 8;
            *(short8*)&AhL[loff] = *(const short8*)(Ah + goff);
            *(short8*)&AmL[loff] = *(const short8*)(Am + goff);
            *(short8*)&AlL[loff] = *(const short8*)(Al + goff);
        }
        __syncthreads();
        f32x4 acc0 = {0.f, 0.f, 0.f, 0.f}, acc1 = {0.f, 0.f, 0.f, 0.f};
#pragma unroll
        for (int tap = 0; tap < 3; ++tap) {
            short8 Brh[KS], Brm[KS], Brl[KS];
#pragma unroll
            for (int ks = 0; ks < KS; ++ks) {
                size_t boff = ((size_t)(tap * 256) + ncol) * CI + ks * 32 + q * 8;
                Brh[ks] = *(const short8*)&Wh[boff];
                Brm[ks] = *(const short8*)&Wm[boff];
                Brl[ks] = *(const short8*)&Wl[boff];
            }
#pragma unroll
            for (int ks = 0; ks < KS; ++ks) {
                int koff = ks * 32 + q * 8;
                int r0 = (lo16 + tap) * STR + koff;
                int r1 = (16 + lo16 + tap) * STR + koff;
                short8 a0h = *(const short8*)&AhL[r0];
                short8 a0m = *(const short8*)&AmL[r0];
                short8 a0l = *(const short8*)&AlL[r0];
                short8 a1h = *(const short8*)&AhL[r1];
                short8 a1m = *(const short8*)&AmL[r1];
                short8 a1l = *(const short8*)&AlL[r1];
                acc0 = __builtin_amdgcn_mfma_f32_16x16x32_bf16(a0h, Brh[ks], acc0, 0, 0, 0);
                acc0 = __builtin_amdgcn_mfma_f32_16x16x32_bf16(a0h, Brm[ks], acc0, 0, 0, 0);
                acc0 = __builtin_amdgcn_mfma_f32_16x16x32_bf16(a0m, Brh[ks], acc0, 0, 0, 0);
                acc0 = __builtin_amdgcn_mfma_f32_16x16x32_bf16(a0h, Brl[ks], acc0, 0, 0, 0);
                acc0 = __builtin_amdgcn_mfma_f32_16x16x32_bf16(a0m, Brm[ks], acc0, 0, 0, 0);
                acc0 = __builtin_amdgcn_mfma_f32_16x16x32_bf16(a0l, Brh[ks], acc0, 0, 0, 0);
                acc1 = __builtin_amdgcn_mfma_f32_16x16x32_bf16(a1h, Brh[ks], acc1, 0, 0, 0);
                acc1 = __builtin_amdgcn_mfma_f32_16x16x32_bf16(a1h, Brm[ks], acc1, 0, 0, 0);
                acc1 = __builtin_amdgcn_mfma_f32_16x16x32_bf16(a1m, Brh[ks], acc1, 0, 0, 0);
                acc1 = __builtin_amdgcn_mfma_f32_16x16x32_bf16(a1h, Brl[ks], acc1, 0, 0, 0);
                acc1 = __builtin_amdgcn_mfma_f32_16x16x32_bf16(a1m, Brm[ks], acc1, 0, 0, 0);
                acc1 = __builtin_amdgcn_mfma_f32_16x16x32_bf16(a1l, Brh[ks], acc1, 0, 0, 0);
            }
        }
#pragma unroll
        for (int mt = 0; mt < 2; ++mt) {
            f32x4 a = mt ? acc1 : acc0;
#pragma unroll
            for (int r = 0; r < 4; ++r) {
                int row = m0 + mt * 16 + q * 4 + r;
                float v = fmaxf(gv * (a[r] + cbv) + bbv, 0.f);
                size_t o = (size_t)row * 256 + ncol;
                split3(v, oh[o], om[o], ol[o]);
            }
        }
    }
}

// ---------------- conv boundary fixup: wave-per-co recompute of rows l=0 and l=2047 ----------------
template <int CI>
__global__ __launch_bounds__(256) void convfix_k(const u16* __restrict__ inh, const u16* __restrict__ inm,
                                                 const u16* __restrict__ inl, const u16* __restrict__ wh,
                                                 const u16* __restrict__ wm, const u16* __restrict__ wl,
                                                 const float* __restrict__ cb, const float* __restrict__ bg,
                                                 const float* __restrict__ bb, u16* __restrict__ oh,
                                                 u16* __restrict__ om, u16* __restrict__ ol) {
    int b = blockIdx.x, side = blockIdx.y;
    int w = threadIdx.x >> 6, lane = threadIdx.x & 63;
    int co = blockIdx.z * 4 + w;
    int l = side ? (LSEQ - 1) : 0;
    int tap0 = side ? 0 : 1;
    float acc = 0.f;
#pragma unroll
    for (int tp = 0; tp < 2; ++tp) {
        int tap = tap0 + tp;
        int li = l + tap - 1;
        size_t ibase = ((size_t)b * LSEQ + li) * CI;
        size_t wbase = ((size_t)(tap * 256) + co) * CI;
        for (int ci = lane; ci < CI; ci += 64)
            acc += rc3(inh, inm, inl, ibase + ci) * rc3(wh, wm, wl, wbase + ci);
    }
    for (int off = 32; off; off >>= 1) acc += __shfl_xor(acc, off, 64);
    if (lane == 0) {
        float v = fmaxf(bg[co] * (acc + cb[co]) + bb[co], 0.f);
        size_t o = ((size_t)b * LSEQ + l) * 256 + co;
        split3(v, oh[o], om[o], ol[o]);
    }
}

// ---------------- LayerNorm, wave-per-row -> split planes ----------------
__global__ __launch_bounds__(256) void ln_k(const float* __restrict__ xin, const float* __restrict__ g,
                                            const float* __restrict__ b, u16* __restrict__ oh,
                                            u16* __restrict__ om, u16* __restrict__ ol) {
    int t = threadIdx.x;
    int w = t >> 6, lane = t & 63;
    size_t row = (size_t)blockIdx.x * 4 + w;
    float4 v = *(const float4*)&xin[row * 256 + lane * 4];
    float s = v.x + v.y + v.z + v.w;
    float qq = v.x * v.x + v.y * v.y + v.z * v.z + v.w * v.w;
    for (int off = 32; off; off >>= 1) {
        s += __shfl_xor(s, off, 64);
        qq += __shfl_xor(qq, off, 64);
    }
    float m = s * (1.f / 256.f);
    float var = qq * (1.f / 256.f) - m * m;
    float r = rsqrtf(var + 1e-5f);
    float4 gg = *(const float4*)&g[lane * 4];
    float4 bb4 = *(const float4*)&b[lane * 4];
    float o0 = (v.x - m) * r * gg.x + bb4.x;
    float o1 = (v.y - m) * r * gg.y + bb4.y;
    float o2 = (v.z - m) * r * gg.z + bb4.z;
    float o3 = (v.w - m) * r * gg.w + bb4.w;
    u16 h[4], mm[4], ll[4];
    split3(o0, h[0], mm[0], ll[0]);
    split3(o1, h[1], mm[1], ll[1]);
    split3(o2, h[2], mm[2], ll[2]);
    split3(o3, h[3], mm[3], ll[3]);
    size_t i = row * 256 + lane * 4;
    uint2 p;
    p.x = (u32)h[0] | ((u32)h[1] << 16); p.y = (u32)h[2] | ((u32)h[3] << 16);
    *(uint2*)&oh[i] = p;
    p.x = (u32)mm[0] | ((u32)mm[1] << 16); p.y = (u32)mm[2] | ((u32)mm[3] << 16);
    *(uint2*)&om[i] = p;
    p.x = (u32)ll[0] | ((u32)ll[1] << 16); p.y = (u32)ll[2] | ((u32)ll[3] << 16);
    *(uint2*)&ol[i] = p;
}

// ---------------- chunked scan pass 1: 4 states/thread, 64 d per block ----------------
__global__ __launch_bounds__(256) void scan1_k(const float* __restrict__ dtbuf, const u16* __restrict__ uh,
                                               const u16* __restrict__ um, const u16* __restrict__ ul,
                                               const float* __restrict__ bc, const float* __restrict__ A_log,
                                               float* __restrict__ stA, float* __restrict__ stB) {
    int c = blockIdx.x, dgq = blockIdx.y;
    int b = blockIdx.z >> 1, dir = blockIdx.z & 1;
    int t = threadIdx.x;
    int dl = t >> 2, ng = t & 3;
    int d = dgq * 64 + dl;
    float4 Alv = *(const float4*)&A_log[(dir * 256 + d) * 16 + ng * 4];
    float Ac0 = -__expf(Alv.x), Ac1 = -__expf(Alv.y), Ac2 = -__expf(Alv.z), Ac3 = -__expf(Alv.w);
    const float* dtp = dtbuf + (size_t)dir * SZ;
    __shared__ __attribute__((aligned(16))) float s_dt[CT * 68];
    __shared__ __attribute__((aligned(16))) float s_u[CT * 68];
    __shared__ __attribute__((aligned(16))) float s_bu[CT * 20];
#pragma unroll
    for (int rep = 0; rep < 2; ++rep) {
        int idx = t + rep * 256;
        int i = idx >> 4, seg = idx & 15;
        int sq = c * CT + i;
        int tt = dir ? (LSEQ - 1 - sq) : sq;
        size_t rowoff = ((size_t)b * LSEQ + tt) * 256 + dgq * 64 + seg * 4;
        *(float4*)&s_dt[i * 68 + seg * 4] = *(const float4*)&dtp[rowoff];
        uint2 hh = *(const uint2*)&uh[rowoff], mm = *(const uint2*)&um[rowoff], ll = *(const uint2*)&ul[rowoff];
        float4 vv;
        vv.x = b2f(hh.x << 16) + b2f(mm.x << 16) + b2f(ll.x << 16);
        vv.y = b2f(hh.x & 0xFFFF0000u) + b2f(mm.x & 0xFFFF0000u) + b2f(ll.x & 0xFFFF0000u);
        vv.z = b2f(hh.y << 16) + b2f(mm.y << 16) + b2f(ll.y << 16);
        vv.w = b2f(hh.y & 0xFFFF0000u) + b2f(mm.y & 0xFFFF0000u) + b2f(ll.y & 0xFFFF0000u);
        *(float4*)&s_u[i * 68 + seg * 4] = vv;
    }
    if (t < 128) {
        int i = t >> 2, seg = t & 3;
        int sq = c * CT + i;
        int tt = dir ? (LSEQ - 1 - sq) : sq;
        *(float4*)&s_bu[i * 20 + seg * 4] = *(const float4*)&bc[((size_t)b * LSEQ + tt) * 64 + dir * 32 + seg * 4];
    }
    __syncthreads();
    float h0 = 0.f, h1 = 0.f, h2 = 0.f, h3 = 0.f;
    float A0 = 1.f, A1 = 1.f, A2 = 1.f, A3 = 1.f;
#pragma unroll
    for (int i = 0; i < CT; ++i) {
        float dtv = s_dt[i * 68 + dl];
        float uv = s_u[i * 68 + dl];
        float4 bu = *(const float4*)&s_bu[i * 20 + ng * 4];
        float du = dtv * uv;
        float a0 = __expf(dtv * Ac0), a1 = __expf(dtv * Ac1), a2 = __expf(dtv * Ac2), a3 = __expf(dtv * Ac3);
        A0 *= a0; A1 *= a1; A2 *= a2; A3 *= a3;
        h0 = a0 * h0 + du * bu.x;
        h1 = a1 * h1 + du * bu.y;
        h2 = a2 * h2 + du * bu.z;
        h3 = a3 * h3 + du * bu.w;
    }
    size_t o = ((size_t)(b * 2 + dir) * NCH + c) * 4096 + dgq * 1024 + dl * 16 + ng * 4;
    float4 av = {A0, A1, A2, A3};
    float4 hv = {h0, h1, h2, h3};
    *(float4*)&stA[o] = av;
    *(float4*)&stB[o] = hv;
}

// ---------------- chunked scan pass 2 (state layout d*16+n, unchanged) ----------------
__global__ __launch_bounds__(256) void scan2_k(const float* __restrict__ stA, const float* __restrict__ stB,
                                               float* __restrict__ stH) {
    int g = blockIdx.x * 256 + threadIdx.x;
    int bd = g >> 12;
    int idx = g & 4095;
    size_t base = (size_t)bd * NCH * 4096 + idx;
    float h = 0.f;
#pragma unroll 8
    for (int c = 0; c < NCH; ++c) {
        stH[base + (size_t)c * 4096] = h;
        h = stA[base + (size_t)c * 4096] * h + stB[base + (size_t)c * 4096];
    }
}

// ---------------- chunked scan pass 3: seeded recompute + 4-wide dot + 2-shuffle reduce ----------------
__global__ __launch_bounds__(256) void scan3_k(const float* __restrict__ dtbuf, const u16* __restrict__ uh,
                                               const u16* __restrict__ um, const u16* __restrict__ ul,
                                               const float* __restrict__ bc, const float* __restrict__ A_log,
                                               const float* __restrict__ Dp, const float* __restrict__ stH,
                                               float* __restrict__ y0, float* __restrict__ y1) {
    int c = blockIdx.x, dgq = blockIdx.y;
    int b = blockIdx.z >> 1, dir = blockIdx.z & 1;
    int t = threadIdx.x;
    int dl = t >> 2, ng = t & 3;
    int d = dgq * 64 + dl;
    float4 Alv = *(const float4*)&A_log[(dir * 256 + d) * 16 + ng * 4];
    float Ac0 = -__expf(Alv.x), Ac1 = -__expf(Alv.y), Ac2 = -__expf(Alv.z), Ac3 = -__expf(Alv.w);
    float Dv = Dp[dir * 256 + d];
    const float* dtp = dtbuf + (size_t)dir * SZ;
    float* yout = dir ? y1 : y0;
    __shared__ __attribute__((aligned(16))) float s_dt[CT * 68];
    __shared__ __attribute__((aligned(16))) float s_u[CT * 68];
    __shared__ __attribute__((aligned(16))) float s_bc[CT * 36];
#pragma unroll
    for (int rep = 0; rep < 2; ++rep) {
        int idx = t + rep * 256;
        int i = idx >> 4, seg = idx & 15;
        int sq = c * CT + i;
        int tt = dir ? (LSEQ - 1 - sq) : sq;
        size_t rowoff = ((size_t)b * LSEQ + tt) * 256 + dgq * 64 + seg * 4;
        *(float4*)&s_dt[i * 68 + seg * 4] = *(const float4*)&dtp[rowoff];
        uint2 hh = *(const uint2*)&uh[rowoff], mm = *(const uint2*)&um[rowoff], ll = *(const uint2*)&ul[rowoff];
        float4 vv;
        vv.x = b2f(hh.x << 16) + b2f(mm.x << 16) + b2f(ll.x << 16);
        vv.y = b2f(hh.x & 0xFFFF0000u) + b2f(mm.x & 0xFFFF0000u) + b2f(ll.x & 0xFFFF0000u);
        vv.z = b2f(hh.y << 16) + b2f(mm.y << 16) + b2f(ll.y << 16);
        vv.w = b2f(hh.y & 0xFFFF0000u) + b2f(mm.y & 0xFFFF0000u) + b2f(ll.y & 0xFFFF0000u);
        *(float4*)&s_u[i * 68 + seg * 4] = vv;
    }
    {
        int i = t >> 3, seg = t & 7;
        int sq = c * CT + i;
        int tt = dir ? (LSEQ - 1 - sq) : sq;
        *(float4*)&s_bc[i * 36 + seg * 4] = *(const float4*)&bc[((size_t)b * LSEQ + tt) * 64 + dir * 32 + seg * 4];
    }
    __syncthreads();
    size_t o = ((size_t)(b * 2 + dir) * NCH + c) * 4096 + dgq * 1024 + dl * 16 + ng * 4;
    float4 hv = *(const float4*)&stH[o];
    float h0 = hv.x, h1 = hv.y, h2 = hv.z, h3 = hv.w;
    int base_sq = c * CT;
#pragma unroll
    for (int i = 0; i < CT; ++i) {
        float dtv = s_dt[i * 68 + dl];
        float uv = s_u[i * 68 + dl];
        float4 bu = *(const float4*)&s_bc[i * 36 + ng * 4];
        float4 cv = *(const float4*)&s_bc[i * 36 + 16 + ng * 4];
        float du = dtv * uv;
        float a0 = __expf(dtv * Ac0), a1 = __expf(dtv * Ac1), a2 = __expf(dtv * Ac2), a3 = __expf(dtv * Ac3);
        h0 = a0 * h0 + du * bu.x;
        h1 = a1 * h1 + du * bu.y;
        h2 = a2 * h2 + du * bu.z;
        h3 = a3 * h3 + du * bu.w;
        float p = h0 * cv.x + h1 * cv.y + h2 * cv.z + h3 * cv.w;
        p += __shfl_xor(p, 1, 64);
        p += __shfl_xor(p, 2, 64);
        if (ng == 0) {
            int sq = base_sq + i;
            int tt = dir ? (LSEQ - 1 - sq) : sq;
            yout[((size_t)b * LSEQ + tt) * 256 + d] = p + uv * Dv;
        }
    }
}

// ---------------- gate -> split planes ----------------
__global__ __launch_bounds__(256) void gate_k(const float* __restrict__ y0, const float* __restrict__ y1,
                                              const float* __restrict__ z, u16* __restrict__ gh,
                                              u16* __restrict__ gm, u16* __restrict__ gl) {
    size_t i = (size_t)blockIdx.x * 256 + threadIdx.x;
    float4 v0 = ((const float4*)y0)[i];
    float4 v1 = ((const float4*)y1)[i];
    float4 vz = ((const float4*)z)[i];
    float g0 = (v0.x + v1.x) * (vz.x / (1.f + __expf(-vz.x)));
    float g1 = (v0.y + v1.y) * (vz.y / (1.f + __expf(-vz.y)));
    float g2 = (v0.z + v1.z) * (vz.z / (1.f + __expf(-vz.z)));
    float g3 = (v0.w + v1.w) * (vz.w / (1.f + __expf(-vz.w)));
    u16 h[4], m[4], l[4];
    split3(g0, h[0], m[0], l[0]);
    split3(g1, h[1], m[1], l[1]);
    split3(g2, h[2], m[2], l[2]);
    split3(g3, h[3], m[3], l[3]);
    uint2 p;
    p.x = (u32)h[0] | ((u32)h[1] << 16); p.y = (u32)h[2] | ((u32)h[3] << 16);
    *(uint2*)&gh[i * 4] = p;
    p.x = (u32)m[0] | ((u32)m[1] << 16); p.y = (u32)m[2] | ((u32)m[3] << 16);
    *(uint2*)&gm[i * 4] = p;
    p.x = (u32)l[0] | ((u32)l[1] << 16); p.y = (u32)l[2] | ((u32)l[3] << 16);
    *(uint2*)&gl[i * 4] = p;
}

// ---------------- means over L (two-stage); x_cnn from split planes ----------------
__global__ __launch_bounds__(256) void mean1_k(const u16* __restrict__ ch, const u16* __restrict__ cm,
                                               const u16* __restrict__ cl, const float* __restrict__ xm,
                                               float* __restrict__ part) {
    int b = blockIdx.x, chk = blockIdx.y, t = threadIdx.x;
    float s1 = 0.f, s2 = 0.f;
    for (int l = chk * 64; l < chk * 64 + 64; ++l) {
        size_t o = ((size_t)b * LSEQ + l) * 256 + t;
        s1 += rc3(ch, cm, cl, o);
        s2 += xm[o];
    }
    part[(b * 32 + chk) * 512 + t] = s1;
    part[(b * 32 + chk) * 512 + 256 + t] = s2;
}

__global__ __launch_bounds__(256) void mean2_k(const float* __restrict__ part, float* __restrict__ xflat) {
    int b = blockIdx.x, t = threadIdx.x;
    float s1 = 0.f, s2 = 0.f;
    for (int ch = 0; ch < 32; ++ch) {
        s1 += part[(b * 32 + ch) * 512 + t];
        s2 += part[(b * 32 + ch) * 512 + 256 + t];
    }
    xflat[b * 528 + t] = s1 * (1.f / 2048.f);
    xflat[b * 528 + 256 + t] = s2 * (1.f / 2048.f);
}

// ---------------- x_main two-stage ----------------
__global__ __launch_bounds__(256) void xmain1_k(const float* __restrict__ x, const float* __restrict__ w1,
                                                float* __restrict__ part2) {
    int b = blockIdx.x, ch = blockIdx.y, t = threadIdx.x;
    float acc = 0.f;
    for (int k = ch * 128; k < ch * 128 + 128; ++k) acc += x[b * LSEQ + k] * w1[k * 256 + t];
    part2[(b * 16 + ch) * 256 + t] = acc;
}

__global__ __launch_bounds__(256) void xmain2_k(const float* __restrict__ part2, const float* __restrict__ b1,
                                                const float* __restrict__ w2, const float* __restrict__ b2,
                                                float* __restrict__ xflat) {
    int b = blockIdx.x, t = threadIdx.x;
    float acc = b1[t];
    for (int ch = 0; ch < 16; ++ch) acc += part2[(b * 16 + ch) * 256 + t];
    __shared__ float h[256];
    h[t] = fmaxf(acc, 0.f);
    __syncthreads();
    if (t < 16) {
        float a2 = b2[t];
        for (int k = 0; k < 256; ++k) a2 += h[k] * w2[k * 16 + t];
        xflat[b * 528 + 512 + t] = a2;
    }
}

// ---------------- main_weights ----------------
__global__ void mew_k(const float* __restrict__ mew, float* __restrict__ outp) {
    int i = blockIdx.x * 256 + threadIdx.x;
    if (i < LSEQ) outp[4 + i] = 1.f / (1.f + __expf(-mew[i]));
}

// ---------------- pair scores ----------------
__global__ __launch_bounds__(256) void scores_k(const float* __restrict__ xm, const int* __restrict__ pairs,
                                                const float* __restrict__ epw, const float* __restrict__ epb,
                                                float* __restrict__ scores) {
    int p = blockIdx.x;
    int t = threadIdx.x;
    int w = t >> 6, lane = t & 63;
    int pi = pairs[2 * p], pj = pairs[2 * p + 1];
    float acc = 0.f;
    for (int c = lane; c < 256; c += 64) {
        acc += xm[((size_t)w * LSEQ + pi) * 256 + c] * epw[c];
        acc += xm[((size_t)w * LSEQ + pj) * 256 + c] * epw[256 + c];
    }
    for (int off = 32; off; off >>= 1) acc += __shfl_xor(acc, off, 64);
    __shared__ float sb[4];
    if (lane == 0) sb[w] = 1.f / (1.f + __expf(-(acc + epb[0])));
    __syncthreads();
    if (t == 0) scores[p] = 0.25f * (sb[0] + sb[1] + sb[2] + sb[3]);
}

// ---------------- top-k (full stable rank of 200) ----------------
__global__ __launch_bounds__(256) void topk_k(const float* __restrict__ scores, const int* __restrict__ pairs,
                                              float* __restrict__ outp) {
    __shared__ float s[200];
    int t = threadIdx.x;
    if (t < 200) s[t] = scores[t];
    __syncthreads();
    if (t < 200) {
        float v = s[t];
        int r = 0;
        for (int q = 0; q < 200; ++q) {
            float u = s[q];
            r += (u > v) || (u == v && q < t);
        }
        outp[2052 + 2 * r] = (float)pairs[2 * t];
        outp[2052 + 2 * r + 1] = (float)pairs[2 * t + 1];
        outp[2452 + r] = v;
    }
}

// ---------------- epi MLP + out head ----------------
__global__ __launch_bounds__(128) void epi_k(const float* __restrict__ xflat, const float* __restrict__ w1,
                                             const float* __restrict__ b1, const float* __restrict__ w2,
                                             const float* __restrict__ b2, const float* __restrict__ w3,
                                             const float* __restrict__ b3, const float* __restrict__ ow1,
                                             const float* __restrict__ ob1, const float* __restrict__ ow2,
                                             const float* __restrict__ ob2, float* __restrict__ outp) {
    int b = blockIdx.x, t = threadIdx.x;
    __shared__ float xb[528], e1[128], e2[64], e3[32], o1[16];
    for (int idx = t; idx < 528; idx += 128) xb[idx] = xflat[b * 528 + idx];
    __syncthreads();
    {
        float a = b1[t];
        for (int k = 0; k < 528; ++k) a += xb[k] * w1[k * 128 + t];
        e1[t] = fmaxf(a, 0.f);
    }
    __syncthreads();
    if (t < 64) {
        float a = b2[t];
        for (int k = 0; k < 128; ++k) a += e1[k] * w2[k * 64 + t];
        e2[t] = fmaxf(a, 0.f);
    }
    __syncthreads();
    if (t < 32) {
        float a = b3[t];
        for (int k = 0; k < 64; ++k) a += e2[k] * w3[k * 32 + t];
        e3[t] = a;
    }
    __syncthreads();
    if (t < 16) {
        float a = ob1[t];
        for (int k = 0; k < 32; ++k) a += e3[k] * ow1[k * 16 + t];
        o1[t] = fmaxf(a, 0.f);
    }
    __syncthreads();
    if (t == 0) {
        float a = ob2[0];
        for (int k = 0; k < 16; ++k) a += o1[k] * ow2[k];
        outp[b] = 1.f / (1.f + __expf(-a));
    }
}

extern "C" void kernel_launch(void* const* d_in, const int* in_sizes, int n_in, void* d_out, int out_size,
                              void* d_ws, size_t ws_size, hipStream_t stream) {
    (void)in_sizes; (void)n_in; (void)out_size; (void)ws_size;
    const float* x = (const float*)d_in[0];
    const int* pairs = (const int*)d_in[1];
    const float* emb_w = (const float*)d_in[2];
    const float* emb_b = (const float*)d_in[3];
    const float* conv0_w = (const float*)d_in[4];
    const float* conv0_b = (const float*)d_in[5];
    const float* bn0_g = (const float*)d_in[6];
    const float* bn0_b = (const float*)d_in[7];
    const float* conv1_w = (const float*)d_in[8];
    const float* conv1_b = (const float*)d_in[9];
    const float* bn1_g = (const float*)d_in[10];
    const float* bn1_b = (const float*)d_in[11];
    const float* conv2_w = (const float*)d_in[12];
    const float* conv2_b = (const float*)d_in[13];
    const float* bn2_g = (const float*)d_in[14];
    const float* bn2_b = (const float*)d_in[15];
    const float* conv3_w = (const float*)d_in[16];
    const float* conv3_b = (const float*)d_in[17];
    const float* bn3_g = (const float*)d_in[18];
    const float* bn3_b = (const float*)d_in[19];
    const float* fp_w = (const float*)d_in[20];
    const float* fp_b = (const float*)d_in[21];
    const float* mb_norm_g = (const float*)d_in[22];
    const float* mb_norm_b = (const float*)d_in[23];
    const float* mb_in_w = (const float*)d_in[24];
    const float* mb_in_b = (const float*)d_in[25];
    const float* mb_A_log = (const float*)d_in[26];
    const float* mb_dt_w = (const float*)d_in[27];
    const float* mb_dt_b = (const float*)d_in[28];
    const float* mb_B_w = (const float*)d_in[29];
    const float* mb_C_w = (const float*)d_in[30];
    const float* mb_D = (const float*)d_in[31];
    const float* mb_out_w = (const float*)d_in[32];
    const float* mb_out_b = (const float*)d_in[33];
    const float* me_w1 = (const float*)d_in[34];
    const float* me_b1 = (const float*)d_in[35];
    const float* me_w2 = (const float*)d_in[36];
    const float* me_b2 = (const float*)d_in[37];
    const float* mew = (const float*)d_in[38];
    const float* ep_w = (const float*)d_in[39];
    const float* ep_b = (const float*)d_in[40];
    const float* epi_w1 = (const float*)d_in[41];
    const float* epi_b1 = (const float*)d_in[42];
    const float* epi_w2 = (const float*)d_in[43];
    const float* epi_b2 = (const float*)d_in[44];
    const float* epi_w3 = (const float*)d_in[45];
    const float* epi_b3 = (const float*)d_in[46];
    const float* out_w1 = (const float*)d_in[47];
    const float* out_b1 = (const float*)d_in[48];
    const float* out_w2 = (const float*)d_in[49];
    const float* out_b2 = (const float*)d_in[50];
    float* outp = (float*)d_out;

    float* ws = (float*)d_ws;
    size_t off = 0;
    auto AL = [&](size_t n) { float* p = ws + off; off += n; return p; };
    float* xm = AL(SZ);
    float* z = AL(SZ);
    float* dtb = AL(2 * SZ); // c0 split planes aliased inside (dead before dt written)
    float* y0 = AL(SZ);      // stA alias
    float* y1 = AL(SZ);      // stB alias
    float* bcb = AL(SZ / 4);
    AL(128);
    float* c1s = AL(SZ + SZ / 2); // 3 planes x SZ u16 ; also ln/gate splits + stH alias
    AL(128);
    float* c2s = AL(SZ + SZ / 2); // also u split planes
    AL(128);
    float* c3s = AL(SZ + SZ / 2);
    AL(128);
    float* wfp = AL(98304);
    float* win = AL(393216);
    float* wdt = AL(393216);
    float* wou = AL(196608);
    float* wc1 = AL(147456);
    float* wc2 = AL(294912);
    float* wc3 = AL(294912);
    float* wbc = AL(49152);
    float* part = AL(65536);
    float* part2 = AL(16384);
    float* xflat = AL(2112);
    float* scoresb = AL(256);

    u16* c0h = (u16*)dtb + 128;
    u16* c0m = c0h + SZ / 2;
    u16* c0l = c0m + SZ / 2;
    u16* c1h = (u16*)c1s; u16* c1m = c1h + SZ; u16* c1l = c1m + SZ;
    u16* c2h = (u16*)c2s; u16* c2m = c2h + SZ; u16* c2l = c2m + SZ;
    u16* c3h = (u16*)c3s; u16* c3m = c3h + SZ; u16* c3l = c3m + SZ;
    float* stH = c1s;
    u16* wfph = (u16*)wfp; u16* wfpm = wfph + 65536; u16* wfpl = wfpm + 65536;
    u16* winh = (u16*)win; u16* winm = winh + 262144; u16* winl = winm + 262144;
    u16* wdth = (u16*)wdt; u16* wdtm = wdth + 262144; u16* wdtl = wdtm + 262144;
    u16* wouh = (u16*)wou; u16* woum = wouh + 131072; u16* woul = woum + 131072;
    u16* wc1h = (u16*)wc1; u16* wc1m = wc1h + 98304; u16* wc1l = wc1m + 98304;
    u16* wc2h = (u16*)wc2; u16* wc2m = wc2h + 196608; u16* wc2l = wc2m + 196608;
    u16* wc3h = (u16*)wc3; u16* wc3m = wc3h + 196608; u16* wc3l = wc3m + 196608;
    u16* wbch = (u16*)wbc; u16* wbcm = wbch + 32768; u16* wbcl = wbcm + 32768;

    // weight prep
    wsplit_t<<<256, 256, 0, stream>>>(fp_w, 256, 256, 65536, wfph, wfpm, wfpl);
    wsplit_t<<<1024, 256, 0, stream>>>(mb_in_w, 256, 512, 262144, winh, winm, winl);
    wsplit_t<<<1024, 256, 0, stream>>>(mb_dt_w, 256, 256, 262144, wdth, wdtm, wdtl);
    wsplit_t<<<512, 256, 0, stream>>>(mb_out_w, 256, 256, 131072, wouh, woum, woul);
    wsplit_conv<<<384, 256, 0, stream>>>(conv1_w, 128, 98304, wc1h, wc1m, wc1l);
    wsplit_conv<<<768, 256, 0, stream>>>(conv2_w, 256, 196608, wc2h, wc2m, wc2l);
    wsplit_conv<<<768, 256, 0, stream>>>(conv3_w, 256, 196608, wc3h, wc3m, wc3l);
    wsplit_bc<<<128, 256, 0, stream>>>(mb_B_w, mb_C_w, wbch, wbcm, wbcl);

    // CNN
    conv0_k<<<4096, 256, 0, stream>>>(x, conv0_w, conv0_b, bn0_g, bn0_b, c0h, c0m, c0l);
    conv_mfma_k<128, 4, 512><<<dim3(128, 2), 512, 0, stream>>>(c0h, c0m, c0l, wc1h, wc1m, wc1l, conv1_b, bn1_g,
                                                               bn1_b, c1h, c1m, c1l);
    convfix_k<128><<<dim3(4, 2, 64), 256, 0, stream>>>(c0h, c0m, c0l, wc1h, wc1m, wc1l, conv1_b, bn1_g, bn1_b,
                                                       c1h, c1m, c1l);
    conv_mfma_k<256, 8, 512><<<dim3(128, 2), 512, 0, stream>>>(c1h, c1m, c1l, wc2h, wc2m, wc2l, conv2_b, bn2_g,
                                                               bn2_b, c2h, c2m, c2l);
    convfix_k<256><<<dim3(4, 2, 64), 256, 0, stream>>>(c1h, c1m, c1l, wc2h, wc2m, wc2l, conv2_b, bn2_g, bn2_b,
                                                       c2h, c2m, c2l);
    conv_mfma_k<256, 8, 512><<<dim3(128, 2), 512, 0, stream>>>(c2h, c2m, c2l, wc3h, wc3m, wc3l, conv3_b, bn3_g,
                                                               bn3_b, c3h, c3m, c3l);
    convfix_k<256><<<dim3(4, 2, 64), 256, 0, stream>>>(c2h, c2m, c2l, wc3h, wc3m, wc3l, conv3_b, bn3_g, bn3_b,
                                                       c3h, c3m, c3l);

    // xm = x_embed + x_cnn@fp_w + fp_b + PE
    mfma_gemm_k<512><<<dim3(128, 2), 512, 0, stream>>>(c3h, c3m, c3l, wfph, wfpm, wfpl, fp_b, MODE_FP, xm,
                                                       nullptr, nullptr, nullptr, nullptr, x, emb_w, emb_b,
                                                       0, 0, 0);

    for (int l = 0; l < 2; ++l) {
        ln_k<<<2048, 256, 0, stream>>>(xm, mb_norm_g + l * 256, mb_norm_b + l * 256, c1h, c1m, c1l);
        mfma_gemm_k<512><<<dim3(128, 4), 512, 0, stream>>>(c1h, c1m, c1l, winh + l * 131072, winm + l * 131072,
                                                           winl + l * 131072, mb_in_b + l * 512, MODE_UZ, z,
                                                           c2h, c2m, c2l, nullptr, nullptr, nullptr, nullptr,
                                                           0, 0, 0);
        mfma_gemm_k<512><<<dim3(128, 2, 2), 512, 0, stream>>>(c2h, c2m, c2l, wdth + 2 * l * 65536,
                                                              wdtm + 2 * l * 65536, wdtl + 2 * l * 65536,
                                                              mb_dt_b + l * 512, MODE_DT, dtb,
                                                              nullptr, nullptr, nullptr, nullptr, nullptr, nullptr,
                                                              nullptr, 65536, 256, (long)SZ);
        mfma_gemm_k<256><<<dim3(128, 1), 256, 0, stream>>>(c2h, c2m, c2l, wbch + l * 16384, wbcm + l * 16384,
                                                           wbcl + l * 16384, nullptr, MODE_BC, bcb,
                                                           nullptr, nullptr, nullptr, nullptr, nullptr, nullptr,
                                                           nullptr, 0, 0, 0);
        scan1_k<<<dim3(NCH, 4, 8), 256, 0, stream>>>(dtb, c2h, c2m, c2l, bcb, mb_A_log + l * 8192, y0, y1);
        scan2_k<<<128, 256, 0, stream>>>(y0, y1, stH);
        scan3_k<<<dim3(NCH, 4, 8), 256, 0, stream>>>(dtb, c2h, c2m, c2l, bcb, mb_A_log + l * 8192, mb_D + l * 512,
                                                     stH, y0, y1);
        gate_k<<<2048, 256, 0, stream>>>(y0, y1, z, c1h, c1m, c1l);
        mfma_gemm_k<512><<<dim3(128, 2), 512, 0, stream>>>(c1h, c1m, c1l, wouh + l * 65536, woum + l * 65536,
                                                           woul + l * 65536, mb_out_b + l * 256, MODE_OUT, xm,
                                                           nullptr, nullptr, nullptr, xm, nullptr, nullptr,
                                                           nullptr, 0, 0, 0);
    }

    // heads
    mean1_k<<<dim3(4, 32), 256, 0, stream>>>(c3h, c3m, c3l, xm, part);
    mean2_k<<<4, 256, 0, stream>>>(part, xflat);
    xmain1_k<<<dim3(4, 16), 256, 0, stream>>>(x, me_w1, part2);
    xmain2_k<<<4, 256, 0, stream>>>(part2, me_b1, me_w2, me_b2, xflat);
    mew_k<<<8, 256, 0, stream>>>(mew, outp);
    scores_k<<<200, 256, 0, stream>>>(xm, pairs, ep_w, ep_b, scoresb);
    topk_k<<<1, 256, 0, stream>>>(scoresb, pairs, outp);
    epi_k<<<4, 128, 0, stream>>>(xflat, epi_w1, epi_b1, epi_w2, epi_b2, epi_w3, epi_b3, out_w1, out_b1, out_w2,
                                 out_b2, outp);
}

// Round 12
// 677.930 us; speedup vs baseline: 1.3919x; 1.0373x over previous
//
#include <hip/hip_runtime.h>
#include <math.h>

typedef unsigned short u16;
typedef unsigned int u32;
typedef __attribute__((ext_vector_type(8))) short short8;
typedef __attribute__((ext_vector_type(4))) float f32x4;

#define BB 4
#define LSEQ 2048
static const size_t SZ = (size_t)BB * LSEQ * 256; // 2097152

#define NCH 64
#define CT 32

__device__ __forceinline__ float b2f(u32 u) { return __uint_as_float(u); }

// 3-way bf16 split: x = h + m + l - eps, |eps| <= 2^-27 |x|
__device__ __forceinline__ void split3(float x, u16& h, u16& m, u16& l) {
    u32 xu = __float_as_uint(x);
    u32 hu = (xu + 0x7FFFu + ((xu >> 16) & 1u)) & 0xFFFF0000u;
    h = (u16)(hu >> 16);
    float r1 = x - b2f(hu);
    u32 r1u = __float_as_uint(r1);
    u32 mu = (r1u + 0x7FFFu + ((r1u >> 16) & 1u)) & 0xFFFF0000u;
    m = (u16)(mu >> 16);
    float r2 = r1 - b2f(mu);
    u32 lu = __float_as_uint(r2);
    l = (u16)((lu + 0x7FFFu + ((lu >> 16) & 1u)) >> 16);
}

__device__ __forceinline__ float rc3(const u16* __restrict__ h, const u16* __restrict__ m,
                                     const u16* __restrict__ l, size_t i) {
    return b2f((u32)h[i] << 16) + b2f((u32)m[i] << 16) + b2f((u32)l[i] << 16);
}

// ---------------- weight transpose+split: W[mat][K][N] -> planes [mat][n][k] ----------------
__global__ void wsplit_t(const float* __restrict__ W, int Kd, int Nd, int total,
                         u16* __restrict__ oh, u16* __restrict__ om, u16* __restrict__ ol) {
    int idx = blockIdx.x * 256 + threadIdx.x;
    if (idx >= total) return;
    int per = Kd * Nd;
    int mat = idx / per;
    int r = idx - mat * per;
    int n = r / Kd;
    int k = r - n * Kd;
    float v = W[(size_t)mat * per + (size_t)k * Nd + n];
    split3(v, oh[idx], om[idx], ol[idx]);
}

// ---------------- conv weight split: w[co][ci][3] -> planes [tap][co][ci] ----------------
__global__ void wsplit_conv(const float* __restrict__ w, int CI, int total,
                            u16* __restrict__ oh, u16* __restrict__ om, u16* __restrict__ ol) {
    int idx = blockIdx.x * 256 + threadIdx.x;
    if (idx >= total) return;
    int ci = idx % CI;
    int tmp = idx / CI;
    int co = tmp & 255;
    int tap = tmp >> 8;
    float v = w[(co * CI + ci) * 3 + tap];
    split3(v, oh[idx], om[idx], ol[idx]);
}

// ---------------- B/C weight split for bcproj GEMM: [layer][n(64)][k(256)] ----------------
__global__ void wsplit_bc(const float* __restrict__ Bw, const float* __restrict__ Cw,
                          u16* __restrict__ oh, u16* __restrict__ om, u16* __restrict__ ol) {
    int idx = blockIdx.x * 256 + threadIdx.x; // 32768 total
    int layer = idx >> 14;
    int r = idx & 16383;
    int n = r >> 8, k = r & 255;
    int dir = n >> 5, which = (n >> 4) & 1, col = n & 15;
    const float* src = which ? Cw : Bw;
    float v = src[layer * 8192 + dir * 4096 + k * 16 + col];
    split3(v, oh[idx], om[idx], ol[idx]);
}

// ---------------- conv0: Ci=1, Co=128 -> split planes (B,L,128) ----------------
__global__ __launch_bounds__(256) void conv0_k(const float* __restrict__ x, const float* __restrict__ w,
                                               const float* __restrict__ cb, const float* __restrict__ g,
                                               const float* __restrict__ bb, u16* __restrict__ oh,
                                               u16* __restrict__ om, u16* __restrict__ ol) {
    int gid = blockIdx.x * 256 + threadIdx.x;
    int co = gid & 127;
    int l = (gid >> 7) & (LSEQ - 1);
    int b = gid >> 18;
    const float* xr = x + (size_t)b * LSEQ;
    float xm1 = (l > 0) ? xr[l - 1] : 0.f;
    float x0 = xr[l];
    float xp1 = (l < LSEQ - 1) ? xr[l + 1] : 0.f;
    float v = xm1 * w[co * 3] + x0 * w[co * 3 + 1] + xp1 * w[co * 3 + 2] + cb[co];
    v = fmaxf(g[co] * v + bb[co], 0.f);
    size_t o = ((size_t)b * LSEQ + l) * 128 + co;
    split3(v, oh[o], om[o], ol[o]);
}

#define MODE_FP 0
#define MODE_UZ 1
#define MODE_DT 2
#define MODE_OUT 3
#define MODE_BC 4

// ---------------- MFMA GEMM: out(8192,N) = A(8192,256) @ W(256,N); 3-split x 6 products ----------------
// grid: (128, N/64, Z). 256 thr = 4 waves; wave = 16 cols; block = 64 rows (2 chunks).
// launch_bounds(256,3): 3 blocks/CU (LDS 50.7KB x3 = 152KB < 160; VGPR <= 170, kernel uses ~128)
__global__ __launch_bounds__(256, 3) void mfma_gemm_k(
    const u16* __restrict__ Ah, const u16* __restrict__ Am, const u16* __restrict__ Al,
    const u16* __restrict__ Bh_, const u16* __restrict__ Bm_, const u16* __restrict__ Bl_,
    const float* __restrict__ bias, int mode, float* __restrict__ outf,
    u16* __restrict__ oh, u16* __restrict__ om, u16* __restrict__ ol,
    const float* __restrict__ resid, const float* __restrict__ xv,
    const float* __restrict__ embw, const float* __restrict__ embb,
    int bz, int biasz, long oz) {
    __shared__ __attribute__((aligned(16))) u16 AhL[32 * 264];
    __shared__ __attribute__((aligned(16))) u16 AmL[32 * 264];
    __shared__ __attribute__((aligned(16))) u16 AlL[32 * 264];
    int t = threadIdx.x;
    int w = t >> 6, l = t & 63;
    int lo16 = l & 15, q = l >> 4;
    int zi = blockIdx.z;
    const u16* bh = Bh_ + (size_t)zi * bz;
    const u16* bm = Bm_ + (size_t)zi * bz;
    const u16* bl = Bl_ + (size_t)zi * bz;
    int ncol = blockIdx.y * 64 + w * 16 + lo16;
    short8 Brh[8], Brm[8], Brl[8];
#pragma unroll
    for (int ks = 0; ks < 8; ++ks) {
        size_t boff = (size_t)ncol * 256 + ks * 32 + q * 8;
        Brh[ks] = *(const short8*)&bh[boff];
        Brm[ks] = *(const short8*)&bm[boff];
        Brl[ks] = *(const short8*)&bl[boff];
    }
    float bv = bias ? bias[biasz * zi + ncol] : 0.f;
    int m_base = blockIdx.x * 64;
    for (int c = 0; c < 2; ++c) {
        int m0 = m_base + c * 32;
        if (c) __syncthreads();
#pragma unroll
        for (int j = 0; j < 4; ++j) {
            int idx = t + j * 256;
            int r = idx >> 5, p = idx & 31;
            size_t goff = (size_t)(m0 + r) * 256 + p * 8;
            int loff = r * 264 + p * 8;
            *(short8*)&AhL[loff] = *(const short8*)&Ah[goff];
            *(short8*)&AmL[loff] = *(const short8*)&Am[goff];
            *(short8*)&AlL[loff] = *(const short8*)&Al[goff];
        }
        __syncthreads();
        f32x4 acc0 = {0.f, 0.f, 0.f, 0.f}, acc1 = {0.f, 0.f, 0.f, 0.f};
#pragma unroll
        for (int ks = 0; ks < 8; ++ks) {
            int koff = ks * 32 + q * 8;
            short8 a0h = *(const short8*)&AhL[lo16 * 264 + koff];
            short8 a0m = *(const short8*)&AmL[lo16 * 264 + koff];
            short8 a0l = *(const short8*)&AlL[lo16 * 264 + koff];
            short8 a1h = *(const short8*)&AhL[(16 + lo16) * 264 + koff];
            short8 a1m = *(const short8*)&AmL[(16 + lo16) * 264 + koff];
            short8 a1l = *(const short8*)&AlL[(16 + lo16) * 264 + koff];
            acc0 = __builtin_amdgcn_mfma_f32_16x16x32_bf16(a0h, Brh[ks], acc0, 0, 0, 0);
            acc0 = __builtin_amdgcn_mfma_f32_16x16x32_bf16(a0h, Brm[ks], acc0, 0, 0, 0);
            acc0 = __builtin_amdgcn_mfma_f32_16x16x32_bf16(a0m, Brh[ks], acc0, 0, 0, 0);
            acc0 = __builtin_amdgcn_mfma_f32_16x16x32_bf16(a0h, Brl[ks], acc0, 0, 0, 0);
            acc0 = __builtin_amdgcn_mfma_f32_16x16x32_bf16(a0m, Brm[ks], acc0, 0, 0, 0);
            acc0 = __builtin_amdgcn_mfma_f32_16x16x32_bf16(a0l, Brh[ks], acc0, 0, 0, 0);
            acc1 = __builtin_amdgcn_mfma_f32_16x16x32_bf16(a1h, Brh[ks], acc1, 0, 0, 0);
            acc1 = __builtin_amdgcn_mfma_f32_16x16x32_bf16(a1h, Brm[ks], acc1, 0, 0, 0);
            acc1 = __builtin_amdgcn_mfma_f32_16x16x32_bf16(a1m, Brh[ks], acc1, 0, 0, 0);
            acc1 = __builtin_amdgcn_mfma_f32_16x16x32_bf16(a1h, Brl[ks], acc1, 0, 0, 0);
            acc1 = __builtin_amdgcn_mfma_f32_16x16x32_bf16(a1m, Brm[ks], acc1, 0, 0, 0);
            acc1 = __builtin_amdgcn_mfma_f32_16x16x32_bf16(a1l, Brh[ks], acc1, 0, 0, 0);
        }
        float freq = 0.f;
        if (mode == MODE_FP) freq = expf(-(float)(ncol & ~1) * (logf(10000.f) / 256.f));
#pragma unroll
        for (int mt = 0; mt < 2; ++mt) {
            f32x4 a = mt ? acc1 : acc0;
#pragma unroll
            for (int r = 0; r < 4; ++r) {
                int row = m0 + mt * 16 + q * 4 + r;
                float v = a[r] + bv;
                size_t o = (size_t)row * 256 + ncol;
                if (mode == MODE_FP) {
                    int li = row & (LSEQ - 1);
                    float ang = (float)li * freq;
                    float pe = (ncol & 1) ? cosf(ang) : sinf(ang);
                    v += xv[row] * embw[ncol] + embb[ncol] + pe;
                    outf[o] = v;
                } else if (mode == MODE_UZ) {
                    if (ncol < 256) {
                        v = v / (1.f + __expf(-v));
                        split3(v, oh[o], om[o], ol[o]);
                    } else {
                        outf[(size_t)row * 256 + ncol - 256] = v;
                    }
                } else if (mode == MODE_DT) {
                    v = (v > 20.f) ? v : log1pf(__expf(v));
                    outf[(size_t)zi * oz + o] = v;
                } else if (mode == MODE_BC) {
                    outf[(size_t)row * 64 + ncol] = v;
                } else {
                    v += resid[o];
                    outf[o] = v;
                }
            }
        }
    }
}

// ---------------- MFMA conv: implicit GEMM over 3 taps, K=CI per tap ----------------
template <int CI, int KS>
__global__ __launch_bounds__(256, 2) void conv_mfma_k(
    const u16* __restrict__ Ah, const u16* __restrict__ Am, const u16* __restrict__ Al,
    const u16* __restrict__ Wh, const u16* __restrict__ Wm, const u16* __restrict__ Wl,
    const float* __restrict__ cb, const float* __restrict__ bg, const float* __restrict__ bb,
    u16* __restrict__ oh, u16* __restrict__ om, u16* __restrict__ ol) {
    const int STR = CI + 8;
    __shared__ __attribute__((aligned(16))) u16 AhL[34 * STR];
    __shared__ __attribute__((aligned(16))) u16 AmL[34 * STR];
    __shared__ __attribute__((aligned(16))) u16 AlL[34 * STR];
    int t = threadIdx.x, w = t >> 6, l = t & 63;
    int lo16 = l & 15, q = l >> 4;
    int ncol = blockIdx.y * 64 + w * 16 + lo16;
    int m_base = blockIdx.x * 64;
    float cbv = cb[ncol], gv = bg[ncol], bbv = bb[ncol];
    for (int c = 0; c < 2; ++c) {
        int m0 = m_base + c * 32;
        if (c) __syncthreads();
        const int PARTS = CI / 8;
        for (int idx = t; idx < 34 * PARTS; idx += 256) {
            int r = idx / PARTS, p = idx - r * PARTS;
            long goff = (long)(m0 - 1 + r) * CI + p * 8;
            int loff = r * STR + p * 8;
            *(short8*)&AhL[loff] = *(const short8*)(Ah + goff);
            *(short8*)&AmL[loff] = *(const short8*)(Am + goff);
            *(short8*)&AlL[loff] = *(const short8*)(Al + goff);
        }
        __syncthreads();
        f32x4 acc0 = {0.f, 0.f, 0.f, 0.f}, acc1 = {0.f, 0.f, 0.f, 0.f};
#pragma unroll
        for (int tap = 0; tap < 3; ++tap) {
            short8 Brh[KS], Brm[KS], Brl[KS];
#pragma unroll
            for (int ks = 0; ks < KS; ++ks) {
                size_t boff = ((size_t)(tap * 256) + ncol) * CI + ks * 32 + q * 8;
                Brh[ks] = *(const short8*)&Wh[boff];
                Brm[ks] = *(const short8*)&Wm[boff];
                Brl[ks] = *(const short8*)&Wl[boff];
            }
#pragma unroll
            for (int ks = 0; ks < KS; ++ks) {
                int koff = ks * 32 + q * 8;
                int r0 = (lo16 + tap) * STR + koff;
                int r1 = (16 + lo16 + tap) * STR + koff;
                short8 a0h = *(const short8*)&AhL[r0];
                short8 a0m = *(const short8*)&AmL[r0];
                short8 a0l = *(const short8*)&AlL[r0];
                short8 a1h = *(const short8*)&AhL[r1];
                short8 a1m = *(const short8*)&AmL[r1];
                short8 a1l = *(const short8*)&AlL[r1];
                acc0 = __builtin_amdgcn_mfma_f32_16x16x32_bf16(a0h, Brh[ks], acc0, 0, 0, 0);
                acc0 = __builtin_amdgcn_mfma_f32_16x16x32_bf16(a0h, Brm[ks], acc0, 0, 0, 0);
                acc0 = __builtin_amdgcn_mfma_f32_16x16x32_bf16(a0m, Brh[ks], acc0, 0, 0, 0);
                acc0 = __builtin_amdgcn_mfma_f32_16x16x32_bf16(a0h, Brl[ks], acc0, 0, 0, 0);
                acc0 = __builtin_amdgcn_mfma_f32_16x16x32_bf16(a0m, Brm[ks], acc0, 0, 0, 0);
                acc0 = __builtin_amdgcn_mfma_f32_16x16x32_bf16(a0l, Brh[ks], acc0, 0, 0, 0);
                acc1 = __builtin_amdgcn_mfma_f32_16x16x32_bf16(a1h, Brh[ks], acc1, 0, 0, 0);
                acc1 = __builtin_amdgcn_mfma_f32_16x16x32_bf16(a1h, Brm[ks], acc1, 0, 0, 0);
                acc1 = __builtin_amdgcn_mfma_f32_16x16x32_bf16(a1m, Brh[ks], acc1, 0, 0, 0);
                acc1 = __builtin_amdgcn_mfma_f32_16x16x32_bf16(a1h, Brl[ks], acc1, 0, 0, 0);
                acc1 = __builtin_amdgcn_mfma_f32_16x16x32_bf16(a1m, Brm[ks], acc1, 0, 0, 0);
                acc1 = __builtin_amdgcn_mfma_f32_16x16x32_bf16(a1l, Brh[ks], acc1, 0, 0, 0);
            }
        }
#pragma unroll
        for (int mt = 0; mt < 2; ++mt) {
            f32x4 a = mt ? acc1 : acc0;
#pragma unroll
            for (int r = 0; r < 4; ++r) {
                int row = m0 + mt * 16 + q * 4 + r;
                float v = fmaxf(gv * (a[r] + cbv) + bbv, 0.f);
                size_t o = (size_t)row * 256 + ncol;
                split3(v, oh[o], om[o], ol[o]);
            }
        }
    }
}

// ---------------- conv boundary fixup: wave-per-co recompute of rows l=0 and l=2047 ----------------
template <int CI>
__global__ __launch_bounds__(256) void convfix_k(const u16* __restrict__ inh, const u16* __restrict__ inm,
                                                 const u16* __restrict__ inl, const u16* __restrict__ wh,
                                                 const u16* __restrict__ wm, const u16* __restrict__ wl,
                                                 const float* __restrict__ cb, const float* __restrict__ bg,
                                                 const float* __restrict__ bb, u16* __restrict__ oh,
                                                 u16* __restrict__ om, u16* __restrict__ ol) {
    int b = blockIdx.x, side = blockIdx.y;
    int w = threadIdx.x >> 6, lane = threadIdx.x & 63;
    int co = blockIdx.z * 4 + w;
    int l = side ? (LSEQ - 1) : 0;
    int tap0 = side ? 0 : 1;
    float acc = 0.f;
#pragma unroll
    for (int tp = 0; tp < 2; ++tp) {
        int tap = tap0 + tp;
        int li = l + tap - 1;
        size_t ibase = ((size_t)b * LSEQ + li) * CI;
        size_t wbase = ((size_t)(tap * 256) + co) * CI;
        for (int ci = lane; ci < CI; ci += 64)
            acc += rc3(inh, inm, inl, ibase + ci) * rc3(wh, wm, wl, wbase + ci);
    }
    for (int off = 32; off; off >>= 1) acc += __shfl_xor(acc, off, 64);
    if (lane == 0) {
        float v = fmaxf(bg[co] * (acc + cb[co]) + bb[co], 0.f);
        size_t o = ((size_t)b * LSEQ + l) * 256 + co;
        split3(v, oh[o], om[o], ol[o]);
    }
}

// ---------------- LayerNorm, wave-per-row -> split planes ----------------
__global__ __launch_bounds__(256) void ln_k(const float* __restrict__ xin, const float* __restrict__ g,
                                            const float* __restrict__ b, u16* __restrict__ oh,
                                            u16* __restrict__ om, u16* __restrict__ ol) {
    int t = threadIdx.x;
    int w = t >> 6, lane = t & 63;
    size_t row = (size_t)blockIdx.x * 4 + w;
    float4 v = *(const float4*)&xin[row * 256 + lane * 4];
    float s = v.x + v.y + v.z + v.w;
    float qq = v.x * v.x + v.y * v.y + v.z * v.z + v.w * v.w;
    for (int off = 32; off; off >>= 1) {
        s += __shfl_xor(s, off, 64);
        qq += __shfl_xor(qq, off, 64);
    }
    float m = s * (1.f / 256.f);
    float var = qq * (1.f / 256.f) - m * m;
    float r = rsqrtf(var + 1e-5f);
    float4 gg = *(const float4*)&g[lane * 4];
    float4 bb4 = *(const float4*)&b[lane * 4];
    float o0 = (v.x - m) * r * gg.x + bb4.x;
    float o1 = (v.y - m) * r * gg.y + bb4.y;
    float o2 = (v.z - m) * r * gg.z + bb4.z;
    float o3 = (v.w - m) * r * gg.w + bb4.w;
    u16 h[4], mm[4], ll[4];
    split3(o0, h[0], mm[0], ll[0]);
    split3(o1, h[1], mm[1], ll[1]);
    split3(o2, h[2], mm[2], ll[2]);
    split3(o3, h[3], mm[3], ll[3]);
    size_t i = row * 256 + lane * 4;
    uint2 p;
    p.x = (u32)h[0] | ((u32)h[1] << 16); p.y = (u32)h[2] | ((u32)h[3] << 16);
    *(uint2*)&oh[i] = p;
    p.x = (u32)mm[0] | ((u32)mm[1] << 16); p.y = (u32)mm[2] | ((u32)mm[3] << 16);
    *(uint2*)&om[i] = p;
    p.x = (u32)ll[0] | ((u32)ll[1] << 16); p.y = (u32)ll[2] | ((u32)ll[3] << 16);
    *(uint2*)&ol[i] = p;
}

// ---------------- chunked scan pass 1: 4 states/thread, 64 d per block ----------------
__global__ __launch_bounds__(256) void scan1_k(const float* __restrict__ dtbuf, const u16* __restrict__ uh,
                                               const u16* __restrict__ um, const u16* __restrict__ ul,
                                               const float* __restrict__ bc, const float* __restrict__ A_log,
                                               float* __restrict__ stA, float* __restrict__ stB) {
    int c = blockIdx.x, dgq = blockIdx.y;
    int b = blockIdx.z >> 1, dir = blockIdx.z & 1;
    int t = threadIdx.x;
    int dl = t >> 2, ng = t & 3;
    int d = dgq * 64 + dl;
    float4 Alv = *(const float4*)&A_log[(dir * 256 + d) * 16 + ng * 4];
    float Ac0 = -__expf(Alv.x), Ac1 = -__expf(Alv.y), Ac2 = -__expf(Alv.z), Ac3 = -__expf(Alv.w);
    const float* dtp = dtbuf + (size_t)dir * SZ;
    __shared__ __attribute__((aligned(16))) float s_dt[CT * 68];
    __shared__ __attribute__((aligned(16))) float s_u[CT * 68];
    __shared__ __attribute__((aligned(16))) float s_bu[CT * 20];
#pragma unroll
    for (int rep = 0; rep < 2; ++rep) {
        int idx = t + rep * 256;
        int i = idx >> 4, seg = idx & 15;
        int sq = c * CT + i;
        int tt = dir ? (LSEQ - 1 - sq) : sq;
        size_t rowoff = ((size_t)b * LSEQ + tt) * 256 + dgq * 64 + seg * 4;
        *(float4*)&s_dt[i * 68 + seg * 4] = *(const float4*)&dtp[rowoff];
        uint2 hh = *(const uint2*)&uh[rowoff], mm = *(const uint2*)&um[rowoff], ll = *(const uint2*)&ul[rowoff];
        float4 vv;
        vv.x = b2f(hh.x << 16) + b2f(mm.x << 16) + b2f(ll.x << 16);
        vv.y = b2f(hh.x & 0xFFFF0000u) + b2f(mm.x & 0xFFFF0000u) + b2f(ll.x & 0xFFFF0000u);
        vv.z = b2f(hh.y << 16) + b2f(mm.y << 16) + b2f(ll.y << 16);
        vv.w = b2f(hh.y & 0xFFFF0000u) + b2f(mm.y & 0xFFFF0000u) + b2f(ll.y & 0xFFFF0000u);
        *(float4*)&s_u[i * 68 + seg * 4] = vv;
    }
    if (t < 128) {
        int i = t >> 2, seg = t & 3;
        int sq = c * CT + i;
        int tt = dir ? (LSEQ - 1 - sq) : sq;
        *(float4*)&s_bu[i * 20 + seg * 4] = *(const float4*)&bc[((size_t)b * LSEQ + tt) * 64 + dir * 32 + seg * 4];
    }
    __syncthreads();
    float h0 = 0.f, h1 = 0.f, h2 = 0.f, h3 = 0.f;
    float A0 = 1.f, A1 = 1.f, A2 = 1.f, A3 = 1.f;
#pragma unroll
    for (int i = 0; i < CT; ++i) {
        float dtv = s_dt[i * 68 + dl];
        float uv = s_u[i * 68 + dl];
        float4 bu = *(const float4*)&s_bu[i * 20 + ng * 4];
        float du = dtv * uv;
        float a0 = __expf(dtv * Ac0), a1 = __expf(dtv * Ac1), a2 = __expf(dtv * Ac2), a3 = __expf(dtv * Ac3);
        A0 *= a0; A1 *= a1; A2 *= a2; A3 *= a3;
        h0 = a0 * h0 + du * bu.x;
        h1 = a1 * h1 + du * bu.y;
        h2 = a2 * h2 + du * bu.z;
        h3 = a3 * h3 + du * bu.w;
    }
    size_t o = ((size_t)(b * 2 + dir) * NCH + c) * 4096 + dgq * 1024 + dl * 16 + ng * 4;
    float4 av = {A0, A1, A2, A3};
    float4 hv = {h0, h1, h2, h3};
    *(float4*)&stA[o] = av;
    *(float4*)&stB[o] = hv;
}

// ---------------- chunked scan pass 2 (state layout d*16+n, unchanged) ----------------
__global__ __launch_bounds__(256) void scan2_k(const float* __restrict__ stA, const float* __restrict__ stB,
                                               float* __restrict__ stH) {
    int g = blockIdx.x * 256 + threadIdx.x;
    int bd = g >> 12;
    int idx = g & 4095;
    size_t base = (size_t)bd * NCH * 4096 + idx;
    float h = 0.f;
#pragma unroll 8
    for (int c = 0; c < NCH; ++c) {
        stH[base + (size_t)c * 4096] = h;
        h = stA[base + (size_t)c * 4096] * h + stB[base + (size_t)c * 4096];
    }
}

// ---------------- chunked scan pass 3: seeded recompute + 4-wide dot + 2-shuffle reduce ----------------
__global__ __launch_bounds__(256) void scan3_k(const float* __restrict__ dtbuf, const u16* __restrict__ uh,
                                               const u16* __restrict__ um, const u16* __restrict__ ul,
                                               const float* __restrict__ bc, const float* __restrict__ A_log,
                                               const float* __restrict__ Dp, const float* __restrict__ stH,
                                               float* __restrict__ y0, float* __restrict__ y1) {
    int c = blockIdx.x, dgq = blockIdx.y;
    int b = blockIdx.z >> 1, dir = blockIdx.z & 1;
    int t = threadIdx.x;
    int dl = t >> 2, ng = t & 3;
    int d = dgq * 64 + dl;
    float4 Alv = *(const float4*)&A_log[(dir * 256 + d) * 16 + ng * 4];
    float Ac0 = -__expf(Alv.x), Ac1 = -__expf(Alv.y), Ac2 = -__expf(Alv.z), Ac3 = -__expf(Alv.w);
    float Dv = Dp[dir * 256 + d];
    const float* dtp = dtbuf + (size_t)dir * SZ;
    float* yout = dir ? y1 : y0;
    __shared__ __attribute__((aligned(16))) float s_dt[CT * 68];
    __shared__ __attribute__((aligned(16))) float s_u[CT * 68];
    __shared__ __attribute__((aligned(16))) float s_bc[CT * 36];
#pragma unroll
    for (int rep = 0; rep < 2; ++rep) {
        int idx = t + rep * 256;
        int i = idx >> 4, seg = idx & 15;
        int sq = c * CT + i;
        int tt = dir ? (LSEQ - 1 - sq) : sq;
        size_t rowoff = ((size_t)b * LSEQ + tt) * 256 + dgq * 64 + seg * 4;
        *(float4*)&s_dt[i * 68 + seg * 4] = *(const float4*)&dtp[rowoff];
        uint2 hh = *(const uint2*)&uh[rowoff], mm = *(const uint2*)&um[rowoff], ll = *(const uint2*)&ul[rowoff];
        float4 vv;
        vv.x = b2f(hh.x << 16) + b2f(mm.x << 16) + b2f(ll.x << 16);
        vv.y = b2f(hh.x & 0xFFFF0000u) + b2f(mm.x & 0xFFFF0000u) + b2f(ll.x & 0xFFFF0000u);
        vv.z = b2f(hh.y << 16) + b2f(mm.y << 16) + b2f(ll.y << 16);
        vv.w = b2f(hh.y & 0xFFFF0000u) + b2f(mm.y & 0xFFFF0000u) + b2f(ll.y & 0xFFFF0000u);
        *(float4*)&s_u[i * 68 + seg * 4] = vv;
    }
    {
        int i = t >> 3, seg = t & 7;
        int sq = c * CT + i;
        int tt = dir ? (LSEQ - 1 - sq) : sq;
        *(float4*)&s_bc[i * 36 + seg * 4] = *(const float4*)&bc[((size_t)b * LSEQ + tt) * 64 + dir * 32 + seg * 4];
    }
    __syncthreads();
    size_t o = ((size_t)(b * 2 + dir) * NCH + c) * 4096 + dgq * 1024 + dl * 16 + ng * 4;
    float4 hv = *(const float4*)&stH[o];
    float h0 = hv.x, h1 = hv.y, h2 = hv.z, h3 = hv.w;
    int base_sq = c * CT;
#pragma unroll
    for (int i = 0; i < CT; ++i) {
        float dtv = s_dt[i * 68 + dl];
        float uv = s_u[i * 68 + dl];
        float4 bu = *(const float4*)&s_bc[i * 36 + ng * 4];
        float4 cv = *(const float4*)&s_bc[i * 36 + 16 + ng * 4];
        float du = dtv * uv;
        float a0 = __expf(dtv * Ac0), a1 = __expf(dtv * Ac1), a2 = __expf(dtv * Ac2), a3 = __expf(dtv * Ac3);
        h0 = a0 * h0 + du * bu.x;
        h1 = a1 * h1 + du * bu.y;
        h2 = a2 * h2 + du * bu.z;
        h3 = a3 * h3 + du * bu.w;
        float p = h0 * cv.x + h1 * cv.y + h2 * cv.z + h3 * cv.w;
        p += __shfl_xor(p, 1, 64);
        p += __shfl_xor(p, 2, 64);
        if (ng == 0) {
            int sq = base_sq + i;
            int tt = dir ? (LSEQ - 1 - sq) : sq;
            yout[((size_t)b * LSEQ + tt) * 256 + d] = p + uv * Dv;
        }
    }
}

// ---------------- gate -> split planes ----------------
__global__ __launch_bounds__(256) void gate_k(const float* __restrict__ y0, const float* __restrict__ y1,
                                              const float* __restrict__ z, u16* __restrict__ gh,
                                              u16* __restrict__ gm, u16* __restrict__ gl) {
    size_t i = (size_t)blockIdx.x * 256 + threadIdx.x;
    float4 v0 = ((const float4*)y0)[i];
    float4 v1 = ((const float4*)y1)[i];
    float4 vz = ((const float4*)z)[i];
    float g0 = (v0.x + v1.x) * (vz.x / (1.f + __expf(-vz.x)));
    float g1 = (v0.y + v1.y) * (vz.y / (1.f + __expf(-vz.y)));
    float g2 = (v0.z + v1.z) * (vz.z / (1.f + __expf(-vz.z)));
    float g3 = (v0.w + v1.w) * (vz.w / (1.f + __expf(-vz.w)));
    u16 h[4], m[4], l[4];
    split3(g0, h[0], m[0], l[0]);
    split3(g1, h[1], m[1], l[1]);
    split3(g2, h[2], m[2], l[2]);
    split3(g3, h[3], m[3], l[3]);
    uint2 p;
    p.x = (u32)h[0] | ((u32)h[1] << 16); p.y = (u32)h[2] | ((u32)h[3] << 16);
    *(uint2*)&gh[i * 4] = p;
    p.x = (u32)m[0] | ((u32)m[1] << 16); p.y = (u32)m[2] | ((u32)m[3] << 16);
    *(uint2*)&gm[i * 4] = p;
    p.x = (u32)l[0] | ((u32)l[1] << 16); p.y = (u32)l[2] | ((u32)l[3] << 16);
    *(uint2*)&gl[i * 4] = p;
}

// ---------------- means over L (two-stage); x_cnn from split planes ----------------
__global__ __launch_bounds__(256) void mean1_k(const u16* __restrict__ ch, const u16* __restrict__ cm,
                                               const u16* __restrict__ cl, const float* __restrict__ xm,
                                               float* __restrict__ part) {
    int b = blockIdx.x, chk = blockIdx.y, t = threadIdx.x;
    float s1 = 0.f, s2 = 0.f;
    for (int l = chk * 64; l < chk * 64 + 64; ++l) {
        size_t o = ((size_t)b * LSEQ + l) * 256 + t;
        s1 += rc3(ch, cm, cl, o);
        s2 += xm[o];
    }
    part[(b * 32 + chk) * 512 + t] = s1;
    part[(b * 32 + chk) * 512 + 256 + t] = s2;
}

__global__ __launch_bounds__(256) void mean2_k(const float* __restrict__ part, float* __restrict__ xflat) {
    int b = blockIdx.x, t = threadIdx.x;
    float s1 = 0.f, s2 = 0.f;
    for (int ch = 0; ch < 32; ++ch) {
        s1 += part[(b * 32 + ch) * 512 + t];
        s2 += part[(b * 32 + ch) * 512 + 256 + t];
    }
    xflat[b * 528 + t] = s1 * (1.f / 2048.f);
    xflat[b * 528 + 256 + t] = s2 * (1.f / 2048.f);
}

// ---------------- x_main two-stage ----------------
__global__ __launch_bounds__(256) void xmain1_k(const float* __restrict__ x, const float* __restrict__ w1,
                                                float* __restrict__ part2) {
    int b = blockIdx.x, ch = blockIdx.y, t = threadIdx.x;
    float acc = 0.f;
    for (int k = ch * 128; k < ch * 128 + 128; ++k) acc += x[b * LSEQ + k] * w1[k * 256 + t];
    part2[(b * 16 + ch) * 256 + t] = acc;
}

__global__ __launch_bounds__(256) void xmain2_k(const float* __restrict__ part2, const float* __restrict__ b1,
                                                const float* __restrict__ w2, const float* __restrict__ b2,
                                                float* __restrict__ xflat) {
    int b = blockIdx.x, t = threadIdx.x;
    float acc = b1[t];
    for (int ch = 0; ch < 16; ++ch) acc += part2[(b * 16 + ch) * 256 + t];
    __shared__ float h[256];
    h[t] = fmaxf(acc, 0.f);
    __syncthreads();
    if (t < 16) {
        float a2 = b2[t];
        for (int k = 0; k < 256; ++k) a2 += h[k] * w2[k * 16 + t];
        xflat[b * 528 + 512 + t] = a2;
    }
}

// ---------------- main_weights ----------------
__global__ void mew_k(const float* __restrict__ mew, float* __restrict__ outp) {
    int i = blockIdx.x * 256 + threadIdx.x;
    if (i < LSEQ) outp[4 + i] = 1.f / (1.f + __expf(-mew[i]));
}

// ---------------- pair scores ----------------
__global__ __launch_bounds__(256) void scores_k(const float* __restrict__ xm, const int* __restrict__ pairs,
                                                const float* __restrict__ epw, const float* __restrict__ epb,
                                                float* __restrict__ scores) {
    int p = blockIdx.x;
    int t = threadIdx.x;
    int w = t >> 6, lane = t & 63;
    int pi = pairs[2 * p], pj = pairs[2 * p + 1];
    float acc = 0.f;
    for (int c = lane; c < 256; c += 64) {
        acc += xm[((size_t)w * LSEQ + pi) * 256 + c] * epw[c];
        acc += xm[((size_t)w * LSEQ + pj) * 256 + c] * epw[256 + c];
    }
    for (int off = 32; off; off >>= 1) acc += __shfl_xor(acc, off, 64);
    __shared__ float sb[4];
    if (lane == 0) sb[w] = 1.f / (1.f + __expf(-(acc + epb[0])));
    __syncthreads();
    if (t == 0) scores[p] = 0.25f * (sb[0] + sb[1] + sb[2] + sb[3]);
}

// ---------------- top-k (full stable rank of 200) ----------------
__global__ __launch_bounds__(256) void topk_k(const float* __restrict__ scores, const int* __restrict__ pairs,
                                              float* __restrict__ outp) {
    __shared__ float s[200];
    int t = threadIdx.x;
    if (t < 200) s[t] = scores[t];
    __syncthreads();
    if (t < 200) {
        float v = s[t];
        int r = 0;
        for (int q = 0; q < 200; ++q) {
            float u = s[q];
            r += (u > v) || (u == v && q < t);
        }
        outp[2052 + 2 * r] = (float)pairs[2 * t];
        outp[2052 + 2 * r + 1] = (float)pairs[2 * t + 1];
        outp[2452 + r] = v;
    }
}

// ---------------- epi MLP + out head ----------------
__global__ __launch_bounds__(128) void epi_k(const float* __restrict__ xflat, const float* __restrict__ w1,
                                             const float* __restrict__ b1, const float* __restrict__ w2,
                                             const float* __restrict__ b2, const float* __restrict__ w3,
                                             const float* __restrict__ b3, const float* __restrict__ ow1,
                                             const float* __restrict__ ob1, const float* __restrict__ ow2,
                                             const float* __restrict__ ob2, float* __restrict__ outp) {
    int b = blockIdx.x, t = threadIdx.x;
    __shared__ float xb[528], e1[128], e2[64], e3[32], o1[16];
    for (int idx = t; idx < 528; idx += 128) xb[idx] = xflat[b * 528 + idx];
    __syncthreads();
    {
        float a = b1[t];
        for (int k = 0; k < 528; ++k) a += xb[k] * w1[k * 128 + t];
        e1[t] = fmaxf(a, 0.f);
    }
    __syncthreads();
    if (t < 64) {
        float a = b2[t];
        for (int k = 0; k < 128; ++k) a += e1[k] * w2[k * 64 + t];
        e2[t] = fmaxf(a, 0.f);
    }
    __syncthreads();
    if (t < 32) {
        float a = b3[t];
        for (int k = 0; k < 64; ++k) a += e2[k] * w3[k * 32 + t];
        e3[t] = a;
    }
    __syncthreads();
    if (t < 16) {
        float a = ob1[t];
        for (int k = 0; k < 32; ++k) a += e3[k] * ow1[k * 16 + t];
        o1[t] = fmaxf(a, 0.f);
    }
    __syncthreads();
    if (t == 0) {
        float a = ob2[0];
        for (int k = 0; k < 16; ++k) a += o1[k] * ow2[k];
        outp[b] = 1.f / (1.f + __expf(-a));
    }
}

extern "C" void kernel_launch(void* const* d_in, const int* in_sizes, int n_in, void* d_out, int out_size,
                              void* d_ws, size_t ws_size, hipStream_t stream) {
    (void)in_sizes; (void)n_in; (void)out_size; (void)ws_size;
    const float* x = (const float*)d_in[0];
    const int* pairs = (const int*)d_in[1];
    const float* emb_w = (const float*)d_in[2];
    const float* emb_b = (const float*)d_in[3];
    const float* conv0_w = (const float*)d_in[4];
    const float* conv0_b = (const float*)d_in[5];
    const float* bn0_g = (const float*)d_in[6];
    const float* bn0_b = (const float*)d_in[7];
    const float* conv1_w = (const float*)d_in[8];
    const float* conv1_b = (const float*)d_in[9];
    const float* bn1_g = (const float*)d_in[10];
    const float* bn1_b = (const float*)d_in[11];
    const float* conv2_w = (const float*)d_in[12];
    const float* conv2_b = (const float*)d_in[13];
    const float* bn2_g = (const float*)d_in[14];
    const float* bn2_b = (const float*)d_in[15];
    const float* conv3_w = (const float*)d_in[16];
    const float* conv3_b = (const float*)d_in[17];
    const float* bn3_g = (const float*)d_in[18];
    const float* bn3_b = (const float*)d_in[19];
    const float* fp_w = (const float*)d_in[20];
    const float* fp_b = (const float*)d_in[21];
    const float* mb_norm_g = (const float*)d_in[22];
    const float* mb_norm_b = (const float*)d_in[23];
    const float* mb_in_w = (const float*)d_in[24];
    const float* mb_in_b = (const float*)d_in[25];
    const float* mb_A_log = (const float*)d_in[26];
    const float* mb_dt_w = (const float*)d_in[27];
    const float* mb_dt_b = (const float*)d_in[28];
    const float* mb_B_w = (const float*)d_in[29];
    const float* mb_C_w = (const float*)d_in[30];
    const float* mb_D = (const float*)d_in[31];
    const float* mb_out_w = (const float*)d_in[32];
    const float* mb_out_b = (const float*)d_in[33];
    const float* me_w1 = (const float*)d_in[34];
    const float* me_b1 = (const float*)d_in[35];
    const float* me_w2 = (const float*)d_in[36];
    const float* me_b2 = (const float*)d_in[37];
    const float* mew = (const float*)d_in[38];
    const float* ep_w = (const float*)d_in[39];
    const float* ep_b = (const float*)d_in[40];
    const float* epi_w1 = (const float*)d_in[41];
    const float* epi_b1 = (const float*)d_in[42];
    const float* epi_w2 = (const float*)d_in[43];
    const float* epi_b2 = (const float*)d_in[44];
    const float* epi_w3 = (const float*)d_in[45];
    const float* epi_b3 = (const float*)d_in[46];
    const float* out_w1 = (const float*)d_in[47];
    const float* out_b1 = (const float*)d_in[48];
    const float* out_w2 = (const float*)d_in[49];
    const float* out_b2 = (const float*)d_in[50];
    float* outp = (float*)d_out;

    float* ws = (float*)d_ws;
    size_t off = 0;
    auto AL = [&](size_t n) { float* p = ws + off; off += n; return p; };
    float* xm = AL(SZ);
    float* z = AL(SZ);
    float* dtb = AL(2 * SZ); // c0 split planes aliased inside (dead before dt written)
    float* y0 = AL(SZ);      // stA alias
    float* y1 = AL(SZ);      // stB alias
    float* bcb = AL(SZ / 4);
    AL(128);
    float* c1s = AL(SZ + SZ / 2); // 3 planes x SZ u16 ; also ln/gate splits + stH alias
    AL(128);
    float* c2s = AL(SZ + SZ / 2); // also u split planes
    AL(128);
    float* c3s = AL(SZ + SZ / 2);
    AL(128);
    float* wfp = AL(98304);
    float* win = AL(393216);
    float* wdt = AL(393216);
    float* wou = AL(196608);
    float* wc1 = AL(147456);
    float* wc2 = AL(294912);
    float* wc3 = AL(294912);
    float* wbc = AL(49152);
    float* part = AL(65536);
    float* part2 = AL(16384);
    float* xflat = AL(2112);
    float* scoresb = AL(256);

    u16* c0h = (u16*)dtb + 128;
    u16* c0m = c0h + SZ / 2;
    u16* c0l = c0m + SZ / 2;
    u16* c1h = (u16*)c1s; u16* c1m = c1h + SZ; u16* c1l = c1m + SZ;
    u16* c2h = (u16*)c2s; u16* c2m = c2h + SZ; u16* c2l = c2m + SZ;
    u16* c3h = (u16*)c3s; u16* c3m = c3h + SZ; u16* c3l = c3m + SZ;
    float* stH = c1s;
    u16* wfph = (u16*)wfp; u16* wfpm = wfph + 65536; u16* wfpl = wfpm + 65536;
    u16* winh = (u16*)win; u16* winm = winh + 262144; u16* winl = winm + 262144;
    u16* wdth = (u16*)wdt; u16* wdtm = wdth + 262144; u16* wdtl = wdtm + 262144;
    u16* wouh = (u16*)wou; u16* woum = wouh + 131072; u16* woul = woum + 131072;
    u16* wc1h = (u16*)wc1; u16* wc1m = wc1h + 98304; u16* wc1l = wc1m + 98304;
    u16* wc2h = (u16*)wc2; u16* wc2m = wc2h + 196608; u16* wc2l = wc2m + 196608;
    u16* wc3h = (u16*)wc3; u16* wc3m = wc3h + 196608; u16* wc3l = wc3m + 196608;
    u16* wbch = (u16*)wbc; u16* wbcm = wbch + 32768; u16* wbcl = wbcm + 32768;

    // weight prep
    wsplit_t<<<256, 256, 0, stream>>>(fp_w, 256, 256, 65536, wfph, wfpm, wfpl);
    wsplit_t<<<1024, 256, 0, stream>>>(mb_in_w, 256, 512, 262144, winh, winm, winl);
    wsplit_t<<<1024, 256, 0, stream>>>(mb_dt_w, 256, 256, 262144, wdth, wdtm, wdtl);
    wsplit_t<<<512, 256, 0, stream>>>(mb_out_w, 256, 256, 131072, wouh, woum, woul);
    wsplit_conv<<<384, 256, 0, stream>>>(conv1_w, 128, 98304, wc1h, wc1m, wc1l);
    wsplit_conv<<<768, 256, 0, stream>>>(conv2_w, 256, 196608, wc2h, wc2m, wc2l);
    wsplit_conv<<<768, 256, 0, stream>>>(conv3_w, 256, 196608, wc3h, wc3m, wc3l);
    wsplit_bc<<<128, 256, 0, stream>>>(mb_B_w, mb_C_w, wbch, wbcm, wbcl);

    // CNN
    conv0_k<<<4096, 256, 0, stream>>>(x, conv0_w, conv0_b, bn0_g, bn0_b, c0h, c0m, c0l);
    conv_mfma_k<128, 4><<<dim3(128, 4), 256, 0, stream>>>(c0h, c0m, c0l, wc1h, wc1m, wc1l, conv1_b, bn1_g, bn1_b,
                                                          c1h, c1m, c1l);
    convfix_k<128><<<dim3(4, 2, 64), 256, 0, stream>>>(c0h, c0m, c0l, wc1h, wc1m, wc1l, conv1_b, bn1_g, bn1_b,
                                                       c1h, c1m, c1l);
    conv_mfma_k<256, 8><<<dim3(128, 4), 256, 0, stream>>>(c1h, c1m, c1l, wc2h, wc2m, wc2l, conv2_b, bn2_g, bn2_b,
                                                          c2h, c2m, c2l);
    convfix_k<256><<<dim3(4, 2, 64), 256, 0, stream>>>(c1h, c1m, c1l, wc2h, wc2m, wc2l, conv2_b, bn2_g, bn2_b,
                                                       c2h, c2m, c2l);
    conv_mfma_k<256, 8><<<dim3(128, 4), 256, 0, stream>>>(c2h, c2m, c2l, wc3h, wc3m, wc3l, conv3_b, bn3_g, bn3_b,
                                                          c3h, c3m, c3l);
    convfix_k<256><<<dim3(4, 2, 64), 256, 0, stream>>>(c2h, c2m, c2l, wc3h, wc3m, wc3l, conv3_b, bn3_g, bn3_b,
                                                       c3h, c3m, c3l);

    // xm = x_embed + x_cnn@fp_w + fp_b + PE
    mfma_gemm_k<<<dim3(128, 4, 1), 256, 0, stream>>>(c3h, c3m, c3l, wfph, wfpm, wfpl, fp_b, MODE_FP, xm,
                                                     nullptr, nullptr, nullptr, nullptr, x, emb_w, emb_b, 0, 0, 0);

    for (int l = 0; l < 2; ++l) {
        ln_k<<<2048, 256, 0, stream>>>(xm, mb_norm_g + l * 256, mb_norm_b + l * 256, c1h, c1m, c1l);
        mfma_gemm_k<<<dim3(128, 8, 1), 256, 0, stream>>>(c1h, c1m, c1l, winh + l * 131072, winm + l * 131072,
                                                         winl + l * 131072, mb_in_b + l * 512, MODE_UZ, z,
                                                         c2h, c2m, c2l, nullptr, nullptr, nullptr, nullptr, 0, 0, 0);
        mfma_gemm_k<<<dim3(128, 4, 2), 256, 0, stream>>>(c2h, c2m, c2l, wdth + 2 * l * 65536, wdtm + 2 * l * 65536,
                                                         wdtl + 2 * l * 65536, mb_dt_b + l * 512, MODE_DT, dtb,
                                                         nullptr, nullptr, nullptr, nullptr, nullptr, nullptr,
                                                         nullptr, 65536, 256, (long)SZ);
        mfma_gemm_k<<<dim3(128, 1, 1), 256, 0, stream>>>(c2h, c2m, c2l, wbch + l * 16384, wbcm + l * 16384,
                                                         wbcl + l * 16384, nullptr, MODE_BC, bcb,
                                                         nullptr, nullptr, nullptr, nullptr, nullptr, nullptr,
                                                         nullptr, 0, 0, 0);
        scan1_k<<<dim3(NCH, 4, 8), 256, 0, stream>>>(dtb, c2h, c2m, c2l, bcb, mb_A_log + l * 8192, y0, y1);
        scan2_k<<<128, 256, 0, stream>>>(y0, y1, stH);
        scan3_k<<<dim3(NCH, 4, 8), 256, 0, stream>>>(dtb, c2h, c2m, c2l, bcb, mb_A_log + l * 8192, mb_D + l * 512,
                                                     stH, y0, y1);
        gate_k<<<2048, 256, 0, stream>>>(y0, y1, z, c1h, c1m, c1l);
        mfma_gemm_k<<<dim3(128, 4, 1), 256, 0, stream>>>(c1h, c1m, c1l, wouh + l * 65536, woum + l * 65536,
                                                         woul + l * 65536, mb_out_b + l * 256, MODE_OUT, xm,
                                                         nullptr, nullptr, nullptr, xm, nullptr, nullptr, nullptr,
                                                         0, 0, 0);
    }

    // heads
    mean1_k<<<dim3(4, 32), 256, 0, stream>>>(c3h, c3m, c3l, xm, part);
    mean2_k<<<4, 256, 0, stream>>>(part, xflat);
    xmain1_k<<<dim3(4, 16), 256, 0, stream>>>(x, me_w1, part2);
    xmain2_k<<<4, 256, 0, stream>>>(part2, me_b1, me_w2, me_b2, xflat);
    mew_k<<<8, 256, 0, stream>>>(mew, outp);
    scores_k<<<200, 256, 0, stream>>>(xm, pairs, ep_w, ep_b, scoresb);
    topk_k<<<1, 256, 0, stream>>>(scoresb, pairs, outp);
    epi_k<<<4, 128, 0, stream>>>(xflat, epi_w1, epi_b1, epi_w2, epi_b2, epi_w3, epi_b3, out_w1, out_b1, out_w2,
                                 out_b2, outp);
}